// Round 1
// baseline (2197.470 us; speedup 1.0000x reference)
//
#include <hip/hip_runtime.h>
#include <cstddef>

#define B_   8
#define N_   1024
#define C_   768
#define NH_  12
#define HD_  64

// ---------------- GEMM: C[M,N] = A[M,K] * W[K,N] (+bias) ----------------
// 64x64 tile, BK=16, 256 threads, 4x4 outputs/thread, float4 LDS reads.
template<bool BIAS>
__global__ __launch_bounds__(256) void gemm_f32(
    const float* __restrict__ A, const float* __restrict__ W,
    const float* __restrict__ bias, float* __restrict__ C,
    int M, int N, int K)
{
    __shared__ float As[16][68];   // A^T tile: [k][m], padded for banks + f4 align
    __shared__ float Bs[16][64];   // [k][n]
    const int tid = threadIdx.x;
    const int tx = tid & 15, ty = tid >> 4;
    const int bm = blockIdx.y * 64, bn = blockIdx.x * 64;
    float acc[4][4] = {};
    for (int k0 = 0; k0 < K; k0 += 16) {
        #pragma unroll
        for (int i = 0; i < 4; ++i) {
            int idx = tid + i * 256;                    // 0..1023
            As[idx & 15][idx >> 4] =
                A[(size_t)(bm + (idx >> 4)) * K + k0 + (idx & 15)];
            Bs[idx >> 6][idx & 63] =
                W[(size_t)(k0 + (idx >> 6)) * N + bn + (idx & 63)];
        }
        __syncthreads();
        #pragma unroll
        for (int kk = 0; kk < 16; ++kk) {
            float4 a4 = *(const float4*)&As[kk][ty * 4];
            float4 b4 = *(const float4*)&Bs[kk][tx * 4];
            const float a[4] = {a4.x, a4.y, a4.z, a4.w};
            const float b[4] = {b4.x, b4.y, b4.z, b4.w};
            #pragma unroll
            for (int i = 0; i < 4; ++i)
                #pragma unroll
                for (int j = 0; j < 4; ++j)
                    acc[i][j] += a[i] * b[j];
        }
        __syncthreads();
    }
    #pragma unroll
    for (int i = 0; i < 4; ++i) {
        int row = bm + ty * 4 + i;
        int col = bn + tx * 4;
        float4 r = make_float4(acc[i][0], acc[i][1], acc[i][2], acc[i][3]);
        if (BIAS) {
            float4 bb = *(const float4*)&bias[col];
            r.x += bb.x; r.y += bb.y; r.z += bb.z; r.w += bb.w;
        }
        *(float4*)&C[(size_t)row * N + col] = r;
    }
}

// ---------------- scores + biases + softmax -> attn (normalized) ----------
// grid (N_/8, NH_, B_), 256 threads. 8 q-rows per block; 32 lanes per row.
__global__ __launch_bounds__(256) void attn_softmax(
    const float* __restrict__ q, const float* __restrict__ k,
    const float* __restrict__ attn_bias, const float* __restrict__ head_bias,
    float* __restrict__ attn_out)
{
    const int rb = blockIdx.x, h = blockIdx.y, b = blockIdx.z;
    __shared__ float qs[8][68];        // 8 q rows (d=64), padded
    __shared__ float ks[32][68];       // 32 k rows, padded
    __shared__ float sc[8][N_];        // scores, 32 KB
    const int tid  = threadIdx.x;
    const int r    = tid >> 5;         // 0..7 (row in block)
    const int lane = tid & 31;
    const int row  = rb * 8 + r;
    const float scale = 0.125f;        // 64^-0.5

    #pragma unroll
    for (int i = 0; i < 2; ++i) {      // 512 elems
        int idx = tid + i * 256;
        int rr = idx >> 6, dd = idx & 63;
        qs[rr][dd] = q[((size_t)(b * N_ + rb * 8 + rr)) * C_ + h * HD_ + dd];
    }

    for (int mt = 0; mt < N_ / 32; ++mt) {
        #pragma unroll
        for (int i = 0; i < 8; ++i) {  // 2048 elems
            int idx = tid + i * 256;
            int rr = idx >> 6, dd = idx & 63;
            ks[rr][dd] = k[((size_t)(b * N_ + mt * 32 + rr)) * C_ + h * HD_ + dd];
        }
        __syncthreads();
        const float4* qrow = (const float4*)qs[r];
        const float4* krow = (const float4*)ks[lane];
        float dot = 0.f;
        #pragma unroll
        for (int j = 0; j < 16; ++j) {
            float4 a = qrow[j], bb = krow[j];
            dot += a.x * bb.x + a.y * bb.y + a.z * bb.z + a.w * bb.w;
        }
        int col = mt * 32 + lane;
        sc[r][col] = dot * scale
                   + attn_bias[(size_t)row * N_ + col]
                   + head_bias[((size_t)h * N_ + row) * N_ + col];
        __syncthreads();
    }

    // softmax over sc[r][0..1023] by 32-lane group (half-wave, same wave)
    float m = -1e30f;
    #pragma unroll
    for (int j = 0; j < 32; ++j) m = fmaxf(m, sc[r][j * 32 + lane]);
    #pragma unroll
    for (int off = 16; off > 0; off >>= 1) m = fmaxf(m, __shfl_xor(m, off, 32));
    float sum = 0.f;
    #pragma unroll
    for (int j = 0; j < 32; ++j) {
        float e = __expf(sc[r][j * 32 + lane] - m);
        sc[r][j * 32 + lane] = e;
        sum += e;
    }
    #pragma unroll
    for (int off = 16; off > 0; off >>= 1) sum += __shfl_xor(sum, off, 32);
    float inv = 1.f / sum;
    float* orow = attn_out + ((size_t)(b * NH_ + h) * N_ + row) * N_;
    #pragma unroll
    for (int j = 0; j < 32; ++j) orow[j * 32 + lane] = sc[r][j * 32 + lane] * inv;
}

// ---------------- PV: h[b,n,h*64+dd] = sum_m attn * v --------------------
// grid (N_/64, NH_, B_), 256 threads; tile 64 rows x 64 dd, K-tile 32.
__global__ __launch_bounds__(256) void pv_kernel(
    const float* __restrict__ attn, const float* __restrict__ v,
    float* __restrict__ hbuf)
{
    const int nb = blockIdx.x, h = blockIdx.y, b = blockIdx.z;
    __shared__ float as_[64][32];      // attn tile (reads are wave-broadcast)
    __shared__ float vs[32][64];
    const int tid = threadIdx.x;
    const int col = tid & 63;          // dd
    const int rg  = tid >> 6;          // 0..3, uniform per wave
    float acc[16] = {};
    for (int m0 = 0; m0 < N_; m0 += 32) {
        #pragma unroll
        for (int i = 0; i < 8; ++i) {
            int idx = tid + i * 256;
            as_[idx >> 5][idx & 31] =
                attn[((size_t)(b * NH_ + h) * N_ + nb * 64 + (idx >> 5)) * N_ + m0 + (idx & 31)];
            vs[idx >> 6][idx & 63] =
                v[((size_t)(b * N_ + m0 + (idx >> 6))) * C_ + h * HD_ + (idx & 63)];
        }
        __syncthreads();
        for (int mm = 0; mm < 32; mm += 4) {
            float v0 = vs[mm + 0][col], v1 = vs[mm + 1][col];
            float v2 = vs[mm + 2][col], v3 = vs[mm + 3][col];
            #pragma unroll
            for (int ii = 0; ii < 16; ++ii) {
                float4 a = *(const float4*)&as_[rg * 16 + ii][mm];
                acc[ii] += a.x * v0 + a.y * v1 + a.z * v2 + a.w * v3;
            }
        }
        __syncthreads();
    }
    #pragma unroll
    for (int ii = 0; ii < 16; ++ii) {
        int row = nb * 64 + rg * 16 + ii;
        hbuf[((size_t)(b * N_ + row)) * C_ + h * HD_ + col] = acc[ii];
    }
}

extern "C" void kernel_launch(void* const* d_in, const int* in_sizes, int n_in,
                              void* d_out, int out_size, void* d_ws, size_t ws_size,
                              hipStream_t stream) {
    const float* x         = (const float*)d_in[0];
    const float* Wq        = (const float*)d_in[1];
    const float* Wk        = (const float*)d_in[2];
    const float* Wv        = (const float*)d_in[3];
    const float* Wproj     = (const float*)d_in[4];
    const float* proj_b    = (const float*)d_in[5];
    const float* attn_bias = (const float*)d_in[6];
    const float* head_bias = (const float*)d_in[7];

    float* out  = (float*)d_out;                       // [B,N,C]
    float* attn = out + (size_t)B_ * N_ * C_;          // [B,NH,N,N]

    float* qb = (float*)d_ws;                          // 25.2 MB each
    float* kb = qb + (size_t)B_ * N_ * C_;
    float* vb = kb + (size_t)B_ * N_ * C_;

    const int M = B_ * N_;
    dim3 gg(C_ / 64, M / 64);

    gemm_f32<false><<<gg, 256, 0, stream>>>(x, Wq, nullptr, qb, M, C_, C_);
    gemm_f32<false><<<gg, 256, 0, stream>>>(x, Wk, nullptr, kb, M, C_, C_);
    gemm_f32<false><<<gg, 256, 0, stream>>>(x, Wv, nullptr, vb, M, C_, C_);

    attn_softmax<<<dim3(N_ / 8, NH_, B_), 256, 0, stream>>>(
        qb, kb, attn_bias, head_bias, attn);

    pv_kernel<<<dim3(N_ / 64, NH_, B_), 256, 0, stream>>>(attn, vb, qb);

    gemm_f32<true><<<gg, 256, 0, stream>>>(qb, Wproj, proj_b, out, M, C_, C_);
}

// Round 2
// 397.110 us; speedup vs baseline: 5.5337x; 5.5337x over previous
//
#include <hip/hip_runtime.h>
#include <cstddef>

#define B_   8
#define N_   1024
#define C_   768
#define NH_  12
#define HD_  64
#define M_   (B_ * N_)   // 8192

typedef __attribute__((ext_vector_type(8))) short  short8;
typedef __attribute__((ext_vector_type(4))) float  f32x4;

__device__ __forceinline__ unsigned short f2b(float f) {
    union { float f; unsigned u; } v; v.f = f;
    unsigned u = v.u;
    return (unsigned short)((u + 0x7FFFu + ((u >> 16) & 1u)) >> 16);
}
__device__ __forceinline__ float b2f(unsigned short s) {
    union { unsigned u; float f; } v; v.u = ((unsigned)s) << 16;
    return v.f;
}

// ---------------- cast x (f32 -> bf16), vectorized ----------------
__global__ __launch_bounds__(256) void cast_x_kernel(const float* __restrict__ x,
                                                     unsigned short* __restrict__ xb) {
    const int n4 = M_ * C_ / 4;  // float4 count
    for (int i = blockIdx.x * blockDim.x + threadIdx.x; i < n4; i += gridDim.x * blockDim.x) {
        float4 v = ((const float4*)x)[i];
        ushort4 o;
        o.x = f2b(v.x); o.y = f2b(v.y); o.z = f2b(v.z); o.w = f2b(v.w);
        ((ushort4*)xb)[i] = o;
    }
}

// ---------------- transpose + cast weights: Wt[e][c] = bf16(W[c][e]) ------
__global__ __launch_bounds__(256) void transpose_cast_kernel(
    const float* __restrict__ w0, const float* __restrict__ w1,
    const float* __restrict__ w2, const float* __restrict__ w3,
    unsigned short* __restrict__ t0, unsigned short* __restrict__ t1,
    unsigned short* __restrict__ t2, unsigned short* __restrict__ t3) {
    const int z = blockIdx.z;
    const float* src = (z == 0) ? w0 : (z == 1) ? w1 : (z == 2) ? w2 : w3;
    unsigned short* dst = (z == 0) ? t0 : (z == 1) ? t1 : (z == 2) ? t2 : t3;
    __shared__ float tile[32][33];
    const int r0 = blockIdx.y * 32, c0 = blockIdx.x * 32;
    const int tx = threadIdx.x & 31, ty = threadIdx.x >> 5;  // ty 0..7
    #pragma unroll
    for (int p = 0; p < 4; ++p)
        tile[ty + 8 * p][tx] = src[(size_t)(r0 + ty + 8 * p) * C_ + c0 + tx];
    __syncthreads();
    #pragma unroll
    for (int p = 0; p < 4; ++p)
        dst[(size_t)(c0 + ty + 8 * p) * C_ + r0 + tx] = f2b(tile[tx][ty + 8 * p]);
}

// ---------------- bf16 MFMA GEMM: C[M,768] = A[M,768] @ Wt^T --------------
// A row-major [M][768] bf16; Wt row-major [768][768] bf16 holding W^T.
// Block 128x64, BK=32, 256 thr = 4 waves (2x2), wave tile 64x32 (4x2 frags).
// MODE 0: bf16 out row-major. MODE 1: bf16 out transposed-per-head (vt).
// MODE 2: f32 out + bias.
template<int MODE>
__global__ __launch_bounds__(256) void gemm_bf16(
    const unsigned short* __restrict__ A, const unsigned short* __restrict__ Bt,
    const float* __restrict__ bias, void* __restrict__ outp) {
    __shared__ unsigned short As[128][40];   // stride 80B (16B-aligned rows)
    __shared__ unsigned short Bs[64][40];
    const int tid = threadIdx.x;
    const int wid = tid >> 6, lane = tid & 63;
    const int ln = lane & 15, g = lane >> 4;
    const int wm = wid >> 1, wn = wid & 1;
    const int bm = blockIdx.y * 128, bn = blockIdx.x * 64;

    f32x4 acc[4][2];
    #pragma unroll
    for (int i = 0; i < 4; ++i)
        #pragma unroll
        for (int j = 0; j < 2; ++j) acc[i][j] = (f32x4)0.f;

    for (int k0 = 0; k0 < C_; k0 += 32) {
        // stage A: 128 rows x 32 bf16
        #pragma unroll
        for (int p = 0; p < 2; ++p) {
            int idx = tid + p * 256;
            int row = idx >> 2, ch = idx & 3;
            *(int4*)&As[row][ch * 8] =
                *(const int4*)&A[(size_t)(bm + row) * C_ + k0 + ch * 8];
        }
        { // stage B: 64 rows x 32 bf16
            int n = tid >> 2, ch = tid & 3;
            *(int4*)&Bs[n][ch * 8] =
                *(const int4*)&Bt[(size_t)(bn + n) * C_ + k0 + ch * 8];
        }
        __syncthreads();
        short8 a[4], b[2];
        #pragma unroll
        for (int mt = 0; mt < 4; ++mt)
            a[mt] = *(const short8*)&As[wm * 64 + mt * 16 + ln][g * 8];
        #pragma unroll
        for (int nt = 0; nt < 2; ++nt)
            b[nt] = *(const short8*)&Bs[wn * 32 + nt * 16 + ln][g * 8];
        #pragma unroll
        for (int mt = 0; mt < 4; ++mt)
            #pragma unroll
            for (int nt = 0; nt < 2; ++nt)
                acc[mt][nt] = __builtin_amdgcn_mfma_f32_16x16x32_bf16(
                    a[mt], b[nt], acc[mt][nt], 0, 0, 0);
        __syncthreads();
    }

    #pragma unroll
    for (int mt = 0; mt < 4; ++mt) {
        #pragma unroll
        for (int nt = 0; nt < 2; ++nt) {
            f32x4 c = acc[mt][nt];
            int rowb = bm + wm * 64 + mt * 16 + g * 4;
            int col  = bn + wn * 32 + nt * 16 + ln;
            if (MODE == 0) {
                unsigned short* o = (unsigned short*)outp;
                #pragma unroll
                for (int i = 0; i < 4; ++i)
                    o[(size_t)(rowb + i) * C_ + col] = f2b(c[i]);
            } else if (MODE == 2) {
                float* o = (float*)outp;
                float bb = bias[col];
                #pragma unroll
                for (int i = 0; i < 4; ++i)
                    o[(size_t)(rowb + i) * C_ + col] = c[i] + bb;
            } else {
                // vt[(b*NH+h)*64+dd][n], n = row within batch (4 consecutive)
                unsigned short* o = (unsigned short*)outp;
                int b = rowb >> 10, n0 = rowb & 1023;
                int h = col >> 6, dd = col & 63;
                ushort4 pk;
                pk.x = f2b(c[0]); pk.y = f2b(c[1]); pk.z = f2b(c[2]); pk.w = f2b(c[3]);
                *(ushort4*)&o[((size_t)((b * NH_ + h) * HD_ + dd)) * N_ + n0] = pk;
            }
        }
    }
}

// ---------------- fused attention: QK^T + biases + softmax + PV -----------
// Grid (N/32, NH, B), 512 thr = 8 waves. Scores bf16 in LDS [32][1024+8pad].
__global__ __launch_bounds__(512) void attn_fused(
    const unsigned short* __restrict__ qb, const unsigned short* __restrict__ kb,
    const unsigned short* __restrict__ vt,
    const float* __restrict__ attn_bias, const float* __restrict__ head_bias,
    float* __restrict__ attn_out, unsigned short* __restrict__ hb) {
    __shared__ unsigned short sc[32][1032];   // row stride 2064B (129*16B)
    const int qb0 = blockIdx.x * 32, h = blockIdx.y, b = blockIdx.z;
    const int tid = threadIdx.x;
    const int wid = tid >> 6, lane = tid & 63;
    const int ln = lane & 15, g = lane >> 4;

    // ---- phase 1: swapped QK^T (A = k-tile, B = q) + scale + biases -> LDS
    {
        short8 qf[2][2];
        #pragma unroll
        for (int Mt = 0; Mt < 2; ++Mt)
            #pragma unroll
            for (int kc = 0; kc < 2; ++kc)
                qf[Mt][kc] = *(const short8*)&qb[
                    (size_t)((b << 10) + qb0 + Mt * 16 + ln) * C_ + h * HD_ + kc * 32 + g * 8];
        const int mb = wid * 128;
        for (int mt = 0; mt < 8; ++mt) {
            const int m0 = mb + mt * 16;
            short8 kf0 = *(const short8*)&kb[
                (size_t)((b << 10) + m0 + ln) * C_ + h * HD_ + g * 8];
            short8 kf1 = *(const short8*)&kb[
                (size_t)((b << 10) + m0 + ln) * C_ + h * HD_ + 32 + g * 8];
            #pragma unroll
            for (int Mt = 0; Mt < 2; ++Mt) {
                f32x4 s = (f32x4)0.f;
                s = __builtin_amdgcn_mfma_f32_16x16x32_bf16(kf0, qf[Mt][0], s, 0, 0, 0);
                s = __builtin_amdgcn_mfma_f32_16x16x32_bf16(kf1, qf[Mt][1], s, 0, 0, 0);
                // D: col(ln) = q offset in Mt tile; rows = m0 + g*4 + i
                const int q = qb0 + Mt * 16 + ln;
                const int mrow = m0 + g * 4;
                float4 ab = *(const float4*)&attn_bias[(size_t)q * N_ + mrow];
                float4 hbb = *(const float4*)&head_bias[((size_t)h * N_ + q) * N_ + mrow];
                ushort4 pk;
                pk.x = f2b(s[0] * 0.125f + ab.x + hbb.x);
                pk.y = f2b(s[1] * 0.125f + ab.y + hbb.y);
                pk.z = f2b(s[2] * 0.125f + ab.z + hbb.z);
                pk.w = f2b(s[3] * 0.125f + ab.w + hbb.w);
                *(ushort4*)&sc[Mt * 16 + ln][mrow] = pk;
            }
        }
    }
    __syncthreads();

    // ---- phase 2: softmax over m (1024) per q-row; 16 threads/row --------
    {
        const int r = tid >> 4, t16 = tid & 15;
        const int q = qb0 + r;
        float mx = -1e30f;
        #pragma unroll
        for (int j = 0; j < 16; ++j) {
            ushort4 v = *(const ushort4*)&sc[r][t16 * 4 + j * 64];
            mx = fmaxf(fmaxf(fmaxf(mx, b2f(v.x)), fmaxf(b2f(v.y), b2f(v.z))), b2f(v.w));
        }
        #pragma unroll
        for (int off = 8; off; off >>= 1) mx = fmaxf(mx, __shfl_xor(mx, off));
        float sum = 0.f;
        #pragma unroll
        for (int j = 0; j < 16; ++j) {
            ushort4 v = *(const ushort4*)&sc[r][t16 * 4 + j * 64];
            sum += __expf(b2f(v.x) - mx) + __expf(b2f(v.y) - mx)
                 + __expf(b2f(v.z) - mx) + __expf(b2f(v.w) - mx);
        }
        #pragma unroll
        for (int off = 8; off; off >>= 1) sum += __shfl_xor(sum, off);
        const float inv = 1.f / sum;
        float* arow = attn_out + (((size_t)(b * NH_ + h) * N_) + q) * N_;
        #pragma unroll
        for (int j = 0; j < 16; ++j) {
            int c0 = t16 * 4 + j * 64;
            ushort4 v = *(const ushort4*)&sc[r][c0];
            float4 o;
            o.x = __expf(b2f(v.x) - mx) * inv;
            o.y = __expf(b2f(v.y) - mx) * inv;
            o.z = __expf(b2f(v.z) - mx) * inv;
            o.w = __expf(b2f(v.w) - mx) * inv;
            *(float4*)&arow[c0] = o;
            ushort4 pk;
            pk.x = f2b(o.x); pk.y = f2b(o.y); pk.z = f2b(o.z); pk.w = f2b(o.w);
            *(ushort4*)&sc[r][c0] = pk;
        }
    }
    __syncthreads();

    // ---- phase 3: PV (A = p from LDS, B = vt from global) ----------------
    {
        const int Mt = wid >> 2, nt = wid & 3;
        f32x4 acc = (f32x4)0.f;
        const unsigned short* vrow = vt +
            ((size_t)((b * NH_ + h) * HD_ + nt * 16 + ln)) * N_;
        for (int kt = 0; kt < 32; ++kt) {
            short8 pa = *(const short8*)&sc[Mt * 16 + ln][kt * 32 + g * 8];
            short8 vb = *(const short8*)&vrow[kt * 32 + g * 8];
            acc = __builtin_amdgcn_mfma_f32_16x16x32_bf16(pa, vb, acc, 0, 0, 0);
        }
        const int col = h * HD_ + nt * 16 + ln;
        #pragma unroll
        for (int i = 0; i < 4; ++i) {
            int q = qb0 + Mt * 16 + g * 4 + i;
            hb[(size_t)((b << 10) + q) * C_ + col] = f2b(acc[i]);
        }
    }
}

extern "C" void kernel_launch(void* const* d_in, const int* in_sizes, int n_in,
                              void* d_out, int out_size, void* d_ws, size_t ws_size,
                              hipStream_t stream) {
    const float* x         = (const float*)d_in[0];
    const float* Wq        = (const float*)d_in[1];
    const float* Wk        = (const float*)d_in[2];
    const float* Wv        = (const float*)d_in[3];
    const float* Wproj     = (const float*)d_in[4];
    const float* proj_b    = (const float*)d_in[5];
    const float* attn_bias = (const float*)d_in[6];
    const float* head_bias = (const float*)d_in[7];

    float* out  = (float*)d_out;                       // [B,N,C]
    float* attn = out + (size_t)B_ * N_ * C_;          // [B,NH,N,N]

    unsigned short* ws = (unsigned short*)d_ws;
    const size_t SZ_X = (size_t)M_ * C_;               // 6291456
    const size_t SZ_W = (size_t)C_ * C_;               // 589824
    unsigned short* xb  = ws;
    unsigned short* wqt = xb + SZ_X;
    unsigned short* wkt = wqt + SZ_W;
    unsigned short* wvt = wkt + SZ_W;
    unsigned short* wpt = wvt + SZ_W;
    unsigned short* qbuf = wpt + SZ_W;
    unsigned short* kbuf = qbuf + SZ_X;
    unsigned short* vtp  = kbuf + SZ_X;
    unsigned short* hb   = xb;   // alias: xb dead after QKV GEMMs

    cast_x_kernel<<<2048, 256, 0, stream>>>(x, xb);
    transpose_cast_kernel<<<dim3(24, 24, 4), 256, 0, stream>>>(
        Wq, Wk, Wv, Wproj, wqt, wkt, wvt, wpt);

    dim3 gg(C_ / 64, M_ / 128);
    gemm_bf16<0><<<gg, 256, 0, stream>>>(xb, wqt, nullptr, qbuf);
    gemm_bf16<0><<<gg, 256, 0, stream>>>(xb, wkt, nullptr, kbuf);
    gemm_bf16<1><<<gg, 256, 0, stream>>>(xb, wvt, nullptr, vtp);

    attn_fused<<<dim3(N_ / 32, NH_, B_), 512, 0, stream>>>(
        qbuf, kbuf, vtp, attn_bias, head_bias, attn, hb);

    gemm_bf16<2><<<gg, 256, 0, stream>>>(hb, wpt, proj_b, out);
}

// Round 3
// 392.602 us; speedup vs baseline: 5.5972x; 1.0115x over previous
//
#include <hip/hip_runtime.h>
#include <cstddef>

#define B_   8
#define N_   1024
#define C_   768
#define NH_  12
#define HD_  64
#define M_   (B_ * N_)   // 8192

typedef __attribute__((ext_vector_type(8))) short  short8;
typedef __attribute__((ext_vector_type(4))) float  f32x4;

__device__ __forceinline__ unsigned short f2b(float f) {
    union { float f; unsigned u; } v; v.f = f;
    unsigned u = v.u;
    return (unsigned short)((u + 0x7FFFu + ((u >> 16) & 1u)) >> 16);
}
__device__ __forceinline__ float b2f(unsigned short s) {
    union { unsigned u; float f; } v; v.u = ((unsigned)s) << 16;
    return v.f;
}

// ---------------- cast x (f32 -> bf16), vectorized ----------------
__global__ __launch_bounds__(256) void cast_x_kernel(const float* __restrict__ x,
                                                     unsigned short* __restrict__ xb) {
    const int n4 = M_ * C_ / 4;
    for (int i = blockIdx.x * blockDim.x + threadIdx.x; i < n4; i += gridDim.x * blockDim.x) {
        float4 v = ((const float4*)x)[i];
        ushort4 o;
        o.x = f2b(v.x); o.y = f2b(v.y); o.z = f2b(v.z); o.w = f2b(v.w);
        ((ushort4*)xb)[i] = o;
    }
}

// ---------------- transpose + cast weights: Wt[e][c] = bf16(W[c][e]) ------
__global__ __launch_bounds__(256) void transpose_cast_kernel(
    const float* __restrict__ w0, const float* __restrict__ w1,
    const float* __restrict__ w2, const float* __restrict__ w3,
    unsigned short* __restrict__ t0, unsigned short* __restrict__ t1,
    unsigned short* __restrict__ t2, unsigned short* __restrict__ t3) {
    const int z = blockIdx.z;
    const float* src = (z == 0) ? w0 : (z == 1) ? w1 : (z == 2) ? w2 : w3;
    unsigned short* dst = (z == 0) ? t0 : (z == 1) ? t1 : (z == 2) ? t2 : t3;
    __shared__ float tile[32][33];
    const int r0 = blockIdx.y * 32, c0 = blockIdx.x * 32;
    const int tx = threadIdx.x & 31, ty = threadIdx.x >> 5;
    #pragma unroll
    for (int p = 0; p < 4; ++p)
        tile[ty + 8 * p][tx] = src[(size_t)(r0 + ty + 8 * p) * C_ + c0 + tx];
    __syncthreads();
    #pragma unroll
    for (int p = 0; p < 4; ++p)
        dst[(size_t)(c0 + ty + 8 * p) * C_ + r0 + tx] = f2b(tile[tx][ty + 8 * p]);
}

// ---------------- QKV GEMM (one dispatch, z selects weight/output) --------
// Block 128x64, BK=32, 256 thr = 4 waves (2x2). z<2: head-major bf16 out
// [b,h,n,d]; z==2: vt layout [b,h,d,n].
__global__ __launch_bounds__(256) void qkv_gemm(
    const unsigned short* __restrict__ A,
    const unsigned short* __restrict__ W0, const unsigned short* __restrict__ W1,
    const unsigned short* __restrict__ W2,
    unsigned short* __restrict__ o0, unsigned short* __restrict__ o1,
    unsigned short* __restrict__ o2) {
    __shared__ unsigned short As[128][40];
    __shared__ unsigned short Bs[64][40];
    const int z = blockIdx.z;
    const unsigned short* Bt = (z == 0) ? W0 : (z == 1) ? W1 : W2;
    const int tid = threadIdx.x;
    const int wid = tid >> 6, lane = tid & 63;
    const int ln = lane & 15, g = lane >> 4;
    const int wm = wid >> 1, wn = wid & 1;
    const int bm = blockIdx.y * 128, bn = blockIdx.x * 64;

    f32x4 acc[4][2];
    #pragma unroll
    for (int i = 0; i < 4; ++i)
        #pragma unroll
        for (int j = 0; j < 2; ++j) acc[i][j] = (f32x4)0.f;

    for (int k0 = 0; k0 < C_; k0 += 32) {
        #pragma unroll
        for (int p = 0; p < 2; ++p) {
            int idx = tid + p * 256;
            int row = idx >> 2, ch = idx & 3;
            *(int4*)&As[row][ch * 8] =
                *(const int4*)&A[(size_t)(bm + row) * C_ + k0 + ch * 8];
        }
        {
            int n = tid >> 2, ch = tid & 3;
            *(int4*)&Bs[n][ch * 8] =
                *(const int4*)&Bt[(size_t)(bn + n) * C_ + k0 + ch * 8];
        }
        __syncthreads();
        short8 a[4], b[2];
        #pragma unroll
        for (int mt = 0; mt < 4; ++mt)
            a[mt] = *(const short8*)&As[wm * 64 + mt * 16 + ln][g * 8];
        #pragma unroll
        for (int nt = 0; nt < 2; ++nt)
            b[nt] = *(const short8*)&Bs[wn * 32 + nt * 16 + ln][g * 8];
        #pragma unroll
        for (int mt = 0; mt < 4; ++mt)
            #pragma unroll
            for (int nt = 0; nt < 2; ++nt)
                acc[mt][nt] = __builtin_amdgcn_mfma_f32_16x16x32_bf16(
                    a[mt], b[nt], acc[mt][nt], 0, 0, 0);
        __syncthreads();
    }

    unsigned short* outp = (z == 0) ? o0 : (z == 1) ? o1 : o2;
    #pragma unroll
    for (int mt = 0; mt < 4; ++mt) {
        #pragma unroll
        for (int nt = 0; nt < 2; ++nt) {
            f32x4 c = acc[mt][nt];
            int rowb = bm + wm * 64 + mt * 16 + g * 4;
            int col  = bn + wn * 32 + nt * 16 + ln;
            int hh = col >> 6, dd = col & 63;
            if (z < 2) {
                #pragma unroll
                for (int i = 0; i < 4; ++i) {
                    int row = rowb + i;
                    int bb = row >> 10, n = row & 1023;
                    outp[((size_t)(bb * NH_ + hh) * N_ + n) * HD_ + dd] = f2b(c[i]);
                }
            } else {
                int bb = rowb >> 10, n0 = rowb & 1023;
                ushort4 pk;
                pk.x = f2b(c[0]); pk.y = f2b(c[1]); pk.z = f2b(c[2]); pk.w = f2b(c[3]);
                *(ushort4*)&outp[((size_t)(bb * NH_ + hh) * HD_ + dd) * N_ + n0] = pk;
            }
        }
    }
}

// ---------------- proj GEMM: out = hb @ Wproj^T + bias (f32) --------------
__global__ __launch_bounds__(256) void proj_gemm(
    const unsigned short* __restrict__ A, const unsigned short* __restrict__ Bt,
    const float* __restrict__ bias, float* __restrict__ outp) {
    __shared__ unsigned short As[128][40];
    __shared__ unsigned short Bs[64][40];
    const int tid = threadIdx.x;
    const int wid = tid >> 6, lane = tid & 63;
    const int ln = lane & 15, g = lane >> 4;
    const int wm = wid >> 1, wn = wid & 1;
    const int bm = blockIdx.y * 128, bn = blockIdx.x * 64;

    f32x4 acc[4][2];
    #pragma unroll
    for (int i = 0; i < 4; ++i)
        #pragma unroll
        for (int j = 0; j < 2; ++j) acc[i][j] = (f32x4)0.f;

    for (int k0 = 0; k0 < C_; k0 += 32) {
        #pragma unroll
        for (int p = 0; p < 2; ++p) {
            int idx = tid + p * 256;
            int row = idx >> 2, ch = idx & 3;
            *(int4*)&As[row][ch * 8] =
                *(const int4*)&A[(size_t)(bm + row) * C_ + k0 + ch * 8];
        }
        {
            int n = tid >> 2, ch = tid & 3;
            *(int4*)&Bs[n][ch * 8] =
                *(const int4*)&Bt[(size_t)(bn + n) * C_ + k0 + ch * 8];
        }
        __syncthreads();
        short8 a[4], b[2];
        #pragma unroll
        for (int mt = 0; mt < 4; ++mt)
            a[mt] = *(const short8*)&As[wm * 64 + mt * 16 + ln][g * 8];
        #pragma unroll
        for (int nt = 0; nt < 2; ++nt)
            b[nt] = *(const short8*)&Bs[wn * 32 + nt * 16 + ln][g * 8];
        #pragma unroll
        for (int mt = 0; mt < 4; ++mt)
            #pragma unroll
            for (int nt = 0; nt < 2; ++nt)
                acc[mt][nt] = __builtin_amdgcn_mfma_f32_16x16x32_bf16(
                    a[mt], b[nt], acc[mt][nt], 0, 0, 0);
        __syncthreads();
    }

    #pragma unroll
    for (int mt = 0; mt < 4; ++mt) {
        #pragma unroll
        for (int nt = 0; nt < 2; ++nt) {
            f32x4 c = acc[mt][nt];
            int rowb = bm + wm * 64 + mt * 16 + g * 4;
            int col  = bn + wn * 32 + nt * 16 + ln;
            float bb = bias[col];
            #pragma unroll
            for (int i = 0; i < 4; ++i)
                outp[(size_t)(rowb + i) * C_ + col] = c[i] + bb;
        }
    }
}

// ---------------- fused attention ----------------------------------------
// Grid (B, N/32, NH) -> blockIdx.x = b (XCD-aligned), y = qblock, z = h.
// 512 thr = 8 waves. sc: 32 rows x 1024 bf16, stride 2048 B, XOR-swizzled.
__global__ __launch_bounds__(512) void attn_fused(
    const unsigned short* __restrict__ qh, const unsigned short* __restrict__ kh,
    const unsigned short* __restrict__ vt,
    const float* __restrict__ attn_bias, const float* __restrict__ head_bias,
    float* __restrict__ attn_out, unsigned short* __restrict__ hb) {
    __shared__ unsigned short sc[32 * 1024];
    __shared__ float sinv[32];
    const int b = blockIdx.x, qb0 = blockIdx.y * 32, h = blockIdx.z;
    const int bh = b * NH_ + h;
    const int tid = threadIdx.x;
    const int wid = tid >> 6, lane = tid & 63;
    const int ln = lane & 15, g = lane >> 4;

    #define SCP(row, m) ((unsigned short*)((char*)sc + (row) * 2048 + \
                         (((m) * 2) ^ (((row) & 7) << 4))))

    // ---- phase 1: swapped QK^T + scale + biases -> LDS (bf16) ------------
    {
        short8 qf[2][2];
        #pragma unroll
        for (int Mt = 0; Mt < 2; ++Mt)
            #pragma unroll
            for (int kc = 0; kc < 2; ++kc)
                qf[Mt][kc] = *(const short8*)&qh[
                    ((size_t)bh * N_ + qb0 + Mt * 16 + ln) * HD_ + kc * 32 + g * 8];
        const int mb = wid * 128;
        const unsigned short* kbase = kh + (size_t)bh * N_ * HD_;
        short8 k0 = *(const short8*)&kbase[(size_t)(mb + ln) * HD_ + g * 8];
        short8 k1 = *(const short8*)&kbase[(size_t)(mb + ln) * HD_ + 32 + g * 8];
        for (int mt = 0; mt < 8; ++mt) {
            const int m0 = mb + mt * 16;
            const int m1 = (mt < 7) ? m0 + 16 : m0;     // clamped prefetch
            short8 n0 = *(const short8*)&kbase[(size_t)(m1 + ln) * HD_ + g * 8];
            short8 n1 = *(const short8*)&kbase[(size_t)(m1 + ln) * HD_ + 32 + g * 8];
            #pragma unroll
            for (int Mt = 0; Mt < 2; ++Mt) {
                f32x4 s = (f32x4)0.f;
                s = __builtin_amdgcn_mfma_f32_16x16x32_bf16(k0, qf[Mt][0], s, 0, 0, 0);
                s = __builtin_amdgcn_mfma_f32_16x16x32_bf16(k1, qf[Mt][1], s, 0, 0, 0);
                const int q = qb0 + Mt * 16 + ln;
                const int mrow = m0 + g * 4;
                float4 ab = *(const float4*)&attn_bias[(size_t)q * N_ + mrow];
                float4 hbb = *(const float4*)&head_bias[((size_t)h * N_ + q) * N_ + mrow];
                ushort4 pk;
                pk.x = f2b(fmaf(s[0], 0.125f, ab.x + hbb.x));
                pk.y = f2b(fmaf(s[1], 0.125f, ab.y + hbb.y));
                pk.z = f2b(fmaf(s[2], 0.125f, ab.z + hbb.z));
                pk.w = f2b(fmaf(s[3], 0.125f, ab.w + hbb.w));
                *(ushort4*)SCP(Mt * 16 + ln, mrow) = pk;
            }
            k0 = n0; k1 = n1;
        }
    }
    __syncthreads();

    // ---- phase 2: softmax; e (unnorm) -> LDS bf16; attn f32 -> global ----
    {
        const int r = tid >> 4, t16 = tid & 15;
        ushort4 er[16];
        float mx = -1e30f;
        #pragma unroll
        for (int j = 0; j < 16; ++j) {
            er[j] = *(const ushort4*)SCP(r, t16 * 4 + j * 64);
            mx = fmaxf(fmaxf(fmaxf(mx, b2f(er[j].x)), fmaxf(b2f(er[j].y), b2f(er[j].z))),
                       b2f(er[j].w));
        }
        #pragma unroll
        for (int off = 8; off; off >>= 1) mx = fmaxf(mx, __shfl_xor(mx, off, 16));
        float sum = 0.f;
        #pragma unroll
        for (int j = 0; j < 16; ++j) {
            float4 e;
            e.x = __expf(b2f(er[j].x) - mx);
            e.y = __expf(b2f(er[j].y) - mx);
            e.z = __expf(b2f(er[j].z) - mx);
            e.w = __expf(b2f(er[j].w) - mx);
            sum += e.x + e.y + e.z + e.w;
            er[j].x = f2b(e.x); er[j].y = f2b(e.y);
            er[j].z = f2b(e.z); er[j].w = f2b(e.w);
            *(ushort4*)SCP(r, t16 * 4 + j * 64) = er[j];
        }
        #pragma unroll
        for (int off = 8; off; off >>= 1) sum += __shfl_xor(sum, off, 16);
        const float inv = 1.f / sum;
        if (t16 == 0) sinv[r] = inv;
        float* arow = attn_out + ((size_t)bh * N_ + qb0 + r) * N_;
        #pragma unroll
        for (int j = 0; j < 16; ++j) {
            float4 o;
            o.x = b2f(er[j].x) * inv;
            o.y = b2f(er[j].y) * inv;
            o.z = b2f(er[j].z) * inv;
            o.w = b2f(er[j].w) * inv;
            *(float4*)&arow[t16 * 4 + j * 64] = o;
        }
    }
    __syncthreads();

    // ---- phase 3: PV with prefetch; scale by 1/sum at the end ------------
    {
        const int Mt = wid >> 2, nt = wid & 3;
        const unsigned short* vrow = vt + ((size_t)bh * HD_ + nt * 16 + ln) * N_;
        f32x4 acc = (f32x4)0.f;
        short8 pa = *(const short8*)SCP(Mt * 16 + ln, g * 8);
        short8 vb = *(const short8*)&vrow[g * 8];
        for (int kt = 0; kt < 32; ++kt) {
            const int knext = (kt < 31) ? kt + 1 : kt;
            short8 npa = *(const short8*)SCP(Mt * 16 + ln, knext * 32 + g * 8);
            short8 nvb = *(const short8*)&vrow[knext * 32 + g * 8];
            acc = __builtin_amdgcn_mfma_f32_16x16x32_bf16(pa, vb, acc, 0, 0, 0);
            pa = npa; vb = nvb;
        }
        #pragma unroll
        for (int i = 0; i < 4; ++i) {
            int q = qb0 + Mt * 16 + g * 4 + i;
            float o = acc[i] * sinv[Mt * 16 + g * 4 + i];
            hb[(size_t)((b << 10) + q) * C_ + h * HD_ + nt * 16 + ln] = f2b(o);
        }
    }
    #undef SCP
}

extern "C" void kernel_launch(void* const* d_in, const int* in_sizes, int n_in,
                              void* d_out, int out_size, void* d_ws, size_t ws_size,
                              hipStream_t stream) {
    const float* x         = (const float*)d_in[0];
    const float* Wq        = (const float*)d_in[1];
    const float* Wk        = (const float*)d_in[2];
    const float* Wv        = (const float*)d_in[3];
    const float* Wproj     = (const float*)d_in[4];
    const float* proj_b    = (const float*)d_in[5];
    const float* attn_bias = (const float*)d_in[6];
    const float* head_bias = (const float*)d_in[7];

    float* out  = (float*)d_out;                       // [B,N,C]
    float* attn = out + (size_t)B_ * N_ * C_;          // [B,NH,N,N]

    unsigned short* ws = (unsigned short*)d_ws;
    const size_t SZ_X = (size_t)M_ * C_;
    const size_t SZ_W = (size_t)C_ * C_;
    unsigned short* xb  = ws;
    unsigned short* wqt = xb + SZ_X;
    unsigned short* wkt = wqt + SZ_W;
    unsigned short* wvt = wkt + SZ_W;
    unsigned short* wpt = wvt + SZ_W;
    unsigned short* qh  = wpt + SZ_W;     // [B,NH,N,64] bf16
    unsigned short* khd = qh + SZ_X;      // [B,NH,N,64] bf16
    unsigned short* vtp = khd + SZ_X;     // [B,NH,64,N] bf16
    unsigned short* hb  = xb;             // alias: xb dead after QKV GEMMs

    cast_x_kernel<<<2048, 256, 0, stream>>>(x, xb);
    transpose_cast_kernel<<<dim3(24, 24, 4), 256, 0, stream>>>(
        Wq, Wk, Wv, Wproj, wqt, wkt, wvt, wpt);

    qkv_gemm<<<dim3(C_ / 64, M_ / 128, 3), 256, 0, stream>>>(
        xb, wqt, wkt, wvt, qh, khd, vtp);

    attn_fused<<<dim3(B_, N_ / 32, NH_), 512, 0, stream>>>(
        qh, khd, vtp, attn_bias, head_bias, attn, hb);

    proj_gemm<<<dim3(C_ / 64, M_ / 128), 256, 0, stream>>>(hb, wpt, proj_b, out);
}

// Round 4
// 323.579 us; speedup vs baseline: 6.7911x; 1.2133x over previous
//
#include <hip/hip_runtime.h>
#include <cstddef>

#define B_   8
#define N_   1024
#define C_   768
#define NH_  12
#define HD_  64
#define M_   (B_ * N_)   // 8192

typedef __attribute__((ext_vector_type(8))) short  short8;
typedef __attribute__((ext_vector_type(4))) float  f32x4;

__device__ __forceinline__ unsigned short f2b(float f) {
    union { float f; unsigned u; } v; v.f = f;
    unsigned u = v.u;
    return (unsigned short)((u + 0x7FFFu + ((u >> 16) & 1u)) >> 16);
}
__device__ __forceinline__ float b2f(unsigned short s) {
    union { unsigned u; float f; } v; v.u = ((unsigned)s) << 16;
    return v.f;
}

// ---------------- cast x (f32 -> bf16), vectorized ----------------
__global__ __launch_bounds__(256) void cast_x_kernel(const float* __restrict__ x,
                                                     unsigned short* __restrict__ xb) {
    const int n4 = M_ * C_ / 4;
    for (int i = blockIdx.x * blockDim.x + threadIdx.x; i < n4; i += gridDim.x * blockDim.x) {
        float4 v = ((const float4*)x)[i];
        ushort4 o;
        o.x = f2b(v.x); o.y = f2b(v.y); o.z = f2b(v.z); o.w = f2b(v.w);
        ((ushort4*)xb)[i] = o;
    }
}

// ---------------- combined bias: bc[h][q][m] = bf16(ab[q][m] + hb[h][q][m])
__global__ __launch_bounds__(256) void bias_combine_kernel(
    const float* __restrict__ ab, const float* __restrict__ hbias,
    unsigned short* __restrict__ bc) {
    const int total4 = NH_ * N_ * N_ / 4;
    const int qm4 = N_ * N_ / 4;
    for (int i = blockIdx.x * blockDim.x + threadIdx.x; i < total4; i += gridDim.x * blockDim.x) {
        int rem = i % qm4;
        float4 a = ((const float4*)ab)[rem];
        float4 h = ((const float4*)hbias)[i];
        ushort4 o;
        o.x = f2b(a.x + h.x); o.y = f2b(a.y + h.y);
        o.z = f2b(a.z + h.z); o.w = f2b(a.w + h.w);
        ((ushort4*)bc)[i] = o;
    }
}

// ---------------- transpose + cast weights: Wt[e][c] = bf16(W[c][e]) ------
__global__ __launch_bounds__(256) void transpose_cast_kernel(
    const float* __restrict__ w0, const float* __restrict__ w1,
    const float* __restrict__ w2, const float* __restrict__ w3,
    unsigned short* __restrict__ t0, unsigned short* __restrict__ t1,
    unsigned short* __restrict__ t2, unsigned short* __restrict__ t3) {
    const int z = blockIdx.z;
    const float* src = (z == 0) ? w0 : (z == 1) ? w1 : (z == 2) ? w2 : w3;
    unsigned short* dst = (z == 0) ? t0 : (z == 1) ? t1 : (z == 2) ? t2 : t3;
    __shared__ float tile[32][33];
    const int r0 = blockIdx.y * 32, c0 = blockIdx.x * 32;
    const int tx = threadIdx.x & 31, ty = threadIdx.x >> 5;
    #pragma unroll
    for (int p = 0; p < 4; ++p)
        tile[ty + 8 * p][tx] = src[(size_t)(r0 + ty + 8 * p) * C_ + c0 + tx];
    __syncthreads();
    #pragma unroll
    for (int p = 0; p < 4; ++p)
        dst[(size_t)(c0 + ty + 8 * p) * C_ + r0 + tx] = f2b(tile[tx][ty + 8 * p]);
}

// ---------------- QKV GEMM (one dispatch, z selects weight/output) --------
__global__ __launch_bounds__(256) void qkv_gemm(
    const unsigned short* __restrict__ A,
    const unsigned short* __restrict__ W0, const unsigned short* __restrict__ W1,
    const unsigned short* __restrict__ W2,
    unsigned short* __restrict__ o0, unsigned short* __restrict__ o1,
    unsigned short* __restrict__ o2) {
    __shared__ unsigned short As[128][40];
    __shared__ unsigned short Bs[64][40];
    const int z = blockIdx.z;
    const unsigned short* Bt = (z == 0) ? W0 : (z == 1) ? W1 : W2;
    const int tid = threadIdx.x;
    const int wid = tid >> 6, lane = tid & 63;
    const int ln = lane & 15, g = lane >> 4;
    const int wm = wid >> 1, wn = wid & 1;
    const int bm = blockIdx.y * 128, bn = blockIdx.x * 64;

    f32x4 acc[4][2];
    #pragma unroll
    for (int i = 0; i < 4; ++i)
        #pragma unroll
        for (int j = 0; j < 2; ++j) acc[i][j] = (f32x4)0.f;

    for (int k0 = 0; k0 < C_; k0 += 32) {
        #pragma unroll
        for (int p = 0; p < 2; ++p) {
            int idx = tid + p * 256;
            int row = idx >> 2, ch = idx & 3;
            *(int4*)&As[row][ch * 8] =
                *(const int4*)&A[(size_t)(bm + row) * C_ + k0 + ch * 8];
        }
        {
            int n = tid >> 2, ch = tid & 3;
            *(int4*)&Bs[n][ch * 8] =
                *(const int4*)&Bt[(size_t)(bn + n) * C_ + k0 + ch * 8];
        }
        __syncthreads();
        short8 a[4], b[2];
        #pragma unroll
        for (int mt = 0; mt < 4; ++mt)
            a[mt] = *(const short8*)&As[wm * 64 + mt * 16 + ln][g * 8];
        #pragma unroll
        for (int nt = 0; nt < 2; ++nt)
            b[nt] = *(const short8*)&Bs[wn * 32 + nt * 16 + ln][g * 8];
        #pragma unroll
        for (int mt = 0; mt < 4; ++mt)
            #pragma unroll
            for (int nt = 0; nt < 2; ++nt)
                acc[mt][nt] = __builtin_amdgcn_mfma_f32_16x16x32_bf16(
                    a[mt], b[nt], acc[mt][nt], 0, 0, 0);
        __syncthreads();
    }

    unsigned short* outp = (z == 0) ? o0 : (z == 1) ? o1 : o2;
    #pragma unroll
    for (int mt = 0; mt < 4; ++mt) {
        #pragma unroll
        for (int nt = 0; nt < 2; ++nt) {
            f32x4 c = acc[mt][nt];
            int rowb = bm + wm * 64 + mt * 16 + g * 4;
            int col  = bn + wn * 32 + nt * 16 + ln;
            int hh = col >> 6, dd = col & 63;
            if (z < 2) {
                #pragma unroll
                for (int i = 0; i < 4; ++i) {
                    int row = rowb + i;
                    int bb = row >> 10, n = row & 1023;
                    outp[((size_t)(bb * NH_ + hh) * N_ + n) * HD_ + dd] = f2b(c[i]);
                }
            } else {
                int bb = rowb >> 10, n0 = rowb & 1023;
                ushort4 pk;
                pk.x = f2b(c[0]); pk.y = f2b(c[1]); pk.z = f2b(c[2]); pk.w = f2b(c[3]);
                *(ushort4*)&outp[((size_t)(bb * NH_ + hh) * HD_ + dd) * N_ + n0] = pk;
            }
        }
    }
}

// ---------------- proj GEMM: out = hb @ Wproj^T + bias (f32) --------------
__global__ __launch_bounds__(256) void proj_gemm(
    const unsigned short* __restrict__ A, const unsigned short* __restrict__ Bt,
    const float* __restrict__ bias, float* __restrict__ outp) {
    __shared__ unsigned short As[128][40];
    __shared__ unsigned short Bs[64][40];
    const int tid = threadIdx.x;
    const int wid = tid >> 6, lane = tid & 63;
    const int ln = lane & 15, g = lane >> 4;
    const int wm = wid >> 1, wn = wid & 1;
    const int bm = blockIdx.y * 128, bn = blockIdx.x * 64;

    f32x4 acc[4][2];
    #pragma unroll
    for (int i = 0; i < 4; ++i)
        #pragma unroll
        for (int j = 0; j < 2; ++j) acc[i][j] = (f32x4)0.f;

    for (int k0 = 0; k0 < C_; k0 += 32) {
        #pragma unroll
        for (int p = 0; p < 2; ++p) {
            int idx = tid + p * 256;
            int row = idx >> 2, ch = idx & 3;
            *(int4*)&As[row][ch * 8] =
                *(const int4*)&A[(size_t)(bm + row) * C_ + k0 + ch * 8];
        }
        {
            int n = tid >> 2, ch = tid & 3;
            *(int4*)&Bs[n][ch * 8] =
                *(const int4*)&Bt[(size_t)(bn + n) * C_ + k0 + ch * 8];
        }
        __syncthreads();
        short8 a[4], b[2];
        #pragma unroll
        for (int mt = 0; mt < 4; ++mt)
            a[mt] = *(const short8*)&As[wm * 64 + mt * 16 + ln][g * 8];
        #pragma unroll
        for (int nt = 0; nt < 2; ++nt)
            b[nt] = *(const short8*)&Bs[wn * 32 + nt * 16 + ln][g * 8];
        #pragma unroll
        for (int mt = 0; mt < 4; ++mt)
            #pragma unroll
            for (int nt = 0; nt < 2; ++nt)
                acc[mt][nt] = __builtin_amdgcn_mfma_f32_16x16x32_bf16(
                    a[mt], b[nt], acc[mt][nt], 0, 0, 0);
        __syncthreads();
    }

    #pragma unroll
    for (int mt = 0; mt < 4; ++mt) {
        #pragma unroll
        for (int nt = 0; nt < 2; ++nt) {
            f32x4 c = acc[mt][nt];
            int rowb = bm + wm * 64 + mt * 16 + g * 4;
            int col  = bn + wn * 32 + nt * 16 + ln;
            float bb = bias[col];
            #pragma unroll
            for (int i = 0; i < 4; ++i)
                outp[(size_t)(rowb + i) * C_ + col] = c[i] + bb;
        }
    }
}

// ---------------- fused attention ----------------------------------------
// Grid (B, N/32, NH). 512 thr = 8 waves. sc: 32x1024 bf16, XOR-swizzled.
__global__ __launch_bounds__(512) void attn_fused(
    const unsigned short* __restrict__ qh, const unsigned short* __restrict__ kh,
    const unsigned short* __restrict__ vt,
    const unsigned short* __restrict__ bias_c,
    float* __restrict__ attn_out, unsigned short* __restrict__ hb) {
    __shared__ unsigned short sc[32 * 1024];
    __shared__ float sinv[32];
    const int b = blockIdx.x, qb0 = blockIdx.y * 32, h = blockIdx.z;
    const int bh = b * NH_ + h;
    const int tid = threadIdx.x;
    const int wid = tid >> 6, lane = tid & 63;
    const int ln = lane & 15, g = lane >> 4;

    #define SCP(row, m) ((unsigned short*)((char*)sc + (row) * 2048 + \
                         (((m) * 2) ^ (((row) & 7) << 4))))

    // ---- phase 1: swapped QK^T + scale + combined bias -> LDS (bf16) -----
    {
        short8 qf[2][2];
        #pragma unroll
        for (int Mt = 0; Mt < 2; ++Mt)
            #pragma unroll
            for (int kc = 0; kc < 2; ++kc)
                qf[Mt][kc] = *(const short8*)&qh[
                    ((size_t)bh * N_ + qb0 + Mt * 16 + ln) * HD_ + kc * 32 + g * 8];
        const int mb = wid * 128;
        const unsigned short* kbase = kh + (size_t)bh * N_ * HD_;
        short8 k0 = *(const short8*)&kbase[(size_t)(mb + ln) * HD_ + g * 8];
        short8 k1 = *(const short8*)&kbase[(size_t)(mb + ln) * HD_ + 32 + g * 8];
        for (int mt = 0; mt < 8; ++mt) {
            const int m0 = mb + mt * 16;
            const int m1 = (mt < 7) ? m0 + 16 : m0;     // clamped prefetch
            short8 n0 = *(const short8*)&kbase[(size_t)(m1 + ln) * HD_ + g * 8];
            short8 n1 = *(const short8*)&kbase[(size_t)(m1 + ln) * HD_ + 32 + g * 8];
            #pragma unroll
            for (int Mt = 0; Mt < 2; ++Mt) {
                f32x4 s = (f32x4)0.f;
                s = __builtin_amdgcn_mfma_f32_16x16x32_bf16(k0, qf[Mt][0], s, 0, 0, 0);
                s = __builtin_amdgcn_mfma_f32_16x16x32_bf16(k1, qf[Mt][1], s, 0, 0, 0);
                const int q = qb0 + Mt * 16 + ln;
                const int mrow = m0 + g * 4;
                ushort4 bc = *(const ushort4*)&bias_c[((size_t)h * N_ + q) * N_ + mrow];
                ushort4 pk;
                pk.x = f2b(fmaf(s[0], 0.125f, b2f(bc.x)));
                pk.y = f2b(fmaf(s[1], 0.125f, b2f(bc.y)));
                pk.z = f2b(fmaf(s[2], 0.125f, b2f(bc.z)));
                pk.w = f2b(fmaf(s[3], 0.125f, b2f(bc.w)));
                *(ushort4*)SCP(Mt * 16 + ln, mrow) = pk;
            }
            k0 = n0; k1 = n1;
        }
    }
    __syncthreads();

    // ---- phase 2: softmax; e (unnorm) -> LDS bf16; attn f32 -> global ----
    {
        const int r = tid >> 4, t16 = tid & 15;
        ushort4 er[16];
        float mx = -1e30f;
        #pragma unroll
        for (int j = 0; j < 16; ++j) {
            er[j] = *(const ushort4*)SCP(r, t16 * 4 + j * 64);
            mx = fmaxf(fmaxf(fmaxf(mx, b2f(er[j].x)), fmaxf(b2f(er[j].y), b2f(er[j].z))),
                       b2f(er[j].w));
        }
        #pragma unroll
        for (int off = 8; off; off >>= 1) mx = fmaxf(mx, __shfl_xor(mx, off, 16));
        float sum = 0.f;
        #pragma unroll
        for (int j = 0; j < 16; ++j) {
            float4 e;
            e.x = __expf(b2f(er[j].x) - mx);
            e.y = __expf(b2f(er[j].y) - mx);
            e.z = __expf(b2f(er[j].z) - mx);
            e.w = __expf(b2f(er[j].w) - mx);
            sum += e.x + e.y + e.z + e.w;
            er[j].x = f2b(e.x); er[j].y = f2b(e.y);
            er[j].z = f2b(e.z); er[j].w = f2b(e.w);
            *(ushort4*)SCP(r, t16 * 4 + j * 64) = er[j];
        }
        #pragma unroll
        for (int off = 8; off; off >>= 1) sum += __shfl_xor(sum, off, 16);
        const float inv = 1.f / sum;
        if (t16 == 0) sinv[r] = inv;
        float* arow = attn_out + ((size_t)bh * N_ + qb0 + r) * N_;
        #pragma unroll
        for (int j = 0; j < 16; ++j) {
            f32x4 o;
            o[0] = b2f(er[j].x) * inv;
            o[1] = b2f(er[j].y) * inv;
            o[2] = b2f(er[j].z) * inv;
            o[3] = b2f(er[j].w) * inv;
            __builtin_nontemporal_store(o, (f32x4*)&arow[t16 * 4 + j * 64]);
        }
    }
    __syncthreads();

    // ---- phase 3: PV with prefetch; scale by 1/sum at the end ------------
    {
        const int Mt = wid >> 2, nt = wid & 3;
        const unsigned short* vrow = vt + ((size_t)bh * HD_ + nt * 16 + ln) * N_;
        f32x4 acc = (f32x4)0.f;
        short8 pa = *(const short8*)SCP(Mt * 16 + ln, g * 8);
        short8 vb = *(const short8*)&vrow[g * 8];
        for (int kt = 0; kt < 32; ++kt) {
            const int knext = (kt < 31) ? kt + 1 : kt;
            short8 npa = *(const short8*)SCP(Mt * 16 + ln, knext * 32 + g * 8);
            short8 nvb = *(const short8*)&vrow[knext * 32 + g * 8];
            acc = __builtin_amdgcn_mfma_f32_16x16x32_bf16(pa, vb, acc, 0, 0, 0);
            pa = npa; vb = nvb;
        }
        #pragma unroll
        for (int i = 0; i < 4; ++i) {
            int q = qb0 + Mt * 16 + g * 4 + i;
            float o = acc[i] * sinv[Mt * 16 + g * 4 + i];
            hb[(size_t)((b << 10) + q) * C_ + h * HD_ + nt * 16 + ln] = f2b(o);
        }
    }
    #undef SCP
}

extern "C" void kernel_launch(void* const* d_in, const int* in_sizes, int n_in,
                              void* d_out, int out_size, void* d_ws, size_t ws_size,
                              hipStream_t stream) {
    const float* x         = (const float*)d_in[0];
    const float* Wq        = (const float*)d_in[1];
    const float* Wk        = (const float*)d_in[2];
    const float* Wv        = (const float*)d_in[3];
    const float* Wproj     = (const float*)d_in[4];
    const float* proj_b    = (const float*)d_in[5];
    const float* attn_bias = (const float*)d_in[6];
    const float* head_bias = (const float*)d_in[7];

    float* out  = (float*)d_out;                       // [B,N,C]
    float* attn = out + (size_t)B_ * N_ * C_;          // [B,NH,N,N]

    unsigned short* ws = (unsigned short*)d_ws;
    const size_t SZ_X = (size_t)M_ * C_;               // 6291456
    const size_t SZ_W = (size_t)C_ * C_;               // 589824
    unsigned short* xb  = ws;
    unsigned short* wqt = xb + SZ_X;
    unsigned short* wkt = wqt + SZ_W;
    unsigned short* wvt = wkt + SZ_W;
    unsigned short* wpt = wvt + SZ_W;
    unsigned short* qh  = wpt + SZ_W;     // [B,NH,N,64] bf16
    unsigned short* khd = qh + SZ_X;      // [B,NH,N,64] bf16
    unsigned short* vtp = khd + SZ_X;     // [B,NH,64,N] bf16
    unsigned short* bc  = vtp + SZ_X;     // [NH,N,N] bf16, 25.2 MB
    unsigned short* hb  = xb;             // alias: xb dead after QKV GEMMs

    cast_x_kernel<<<2048, 256, 0, stream>>>(x, xb);
    bias_combine_kernel<<<2048, 256, 0, stream>>>(attn_bias, head_bias, bc);
    transpose_cast_kernel<<<dim3(24, 24, 4), 256, 0, stream>>>(
        Wq, Wk, Wv, Wproj, wqt, wkt, wvt, wpt);

    qkv_gemm<<<dim3(C_ / 64, M_ / 128, 3), 256, 0, stream>>>(
        xb, wqt, wkt, wvt, qh, khd, vtp);

    attn_fused<<<dim3(B_, N_ / 32, NH_), 512, 0, stream>>>(
        qh, khd, vtp, bc, attn, hb);

    proj_gemm<<<dim3(C_ / 64, M_ / 128), 256, 0, stream>>>(hb, wpt, proj_b, out);
}

// Round 5
// 310.341 us; speedup vs baseline: 7.0808x; 1.0427x over previous
//
#include <hip/hip_runtime.h>
#include <cstddef>

#define B_   8
#define N_   1024
#define C_   768
#define NH_  12
#define HD_  64
#define M_   (B_ * N_)   // 8192

typedef __attribute__((ext_vector_type(8))) short  short8;
typedef __attribute__((ext_vector_type(4))) float  f32x4;

__device__ __forceinline__ unsigned short f2b(float f) {
    union { float f; unsigned u; } v; v.f = f;
    unsigned u = v.u;
    return (unsigned short)((u + 0x7FFFu + ((u >> 16) & 1u)) >> 16);
}
__device__ __forceinline__ float b2f(unsigned short s) {
    union { unsigned u; float f; } v; v.u = ((unsigned)s) << 16;
    return v.f;
}

// ---------------- cast x (f32 -> bf16), vectorized ----------------
__global__ __launch_bounds__(256) void cast_x_kernel(const float* __restrict__ x,
                                                     unsigned short* __restrict__ xb) {
    const int n4 = M_ * C_ / 4;
    for (int i = blockIdx.x * blockDim.x + threadIdx.x; i < n4; i += gridDim.x * blockDim.x) {
        float4 v = ((const float4*)x)[i];
        ushort4 o;
        o.x = f2b(v.x); o.y = f2b(v.y); o.z = f2b(v.z); o.w = f2b(v.w);
        ((ushort4*)xb)[i] = o;
    }
}

// ---------------- combined bias: bc[h][q][m] = bf16(ab[q][m] + hb[h][q][m])
__global__ __launch_bounds__(256) void bias_combine_kernel(
    const float* __restrict__ ab, const float* __restrict__ hbias,
    unsigned short* __restrict__ bc) {
    const int total4 = NH_ * N_ * N_ / 4;
    const int qm4 = N_ * N_ / 4;
    for (int i = blockIdx.x * blockDim.x + threadIdx.x; i < total4; i += gridDim.x * blockDim.x) {
        int rem = i % qm4;
        float4 a = ((const float4*)ab)[rem];
        float4 h = ((const float4*)hbias)[i];
        ushort4 o;
        o.x = f2b(a.x + h.x); o.y = f2b(a.y + h.y);
        o.z = f2b(a.z + h.z); o.w = f2b(a.w + h.w);
        ((ushort4*)bc)[i] = o;
    }
}

// ---------------- transpose + cast weights: Wt[e][c] = bf16(W[c][e]) ------
__global__ __launch_bounds__(256) void transpose_cast_kernel(
    const float* __restrict__ w0, const float* __restrict__ w1,
    const float* __restrict__ w2, const float* __restrict__ w3,
    unsigned short* __restrict__ t0, unsigned short* __restrict__ t1,
    unsigned short* __restrict__ t2, unsigned short* __restrict__ t3) {
    const int z = blockIdx.z;
    const float* src = (z == 0) ? w0 : (z == 1) ? w1 : (z == 2) ? w2 : w3;
    unsigned short* dst = (z == 0) ? t0 : (z == 1) ? t1 : (z == 2) ? t2 : t3;
    __shared__ float tile[32][33];
    const int r0 = blockIdx.y * 32, c0 = blockIdx.x * 32;
    const int tx = threadIdx.x & 31, ty = threadIdx.x >> 5;
    #pragma unroll
    for (int p = 0; p < 4; ++p)
        tile[ty + 8 * p][tx] = src[(size_t)(r0 + ty + 8 * p) * C_ + c0 + tx];
    __syncthreads();
    #pragma unroll
    for (int p = 0; p < 4; ++p)
        dst[(size_t)(c0 + ty + 8 * p) * C_ + r0 + tx] = f2b(tile[tx][ty + 8 * p]);
}

// ---------------- QKV GEMM (one dispatch, z selects weight/output) --------
__global__ __launch_bounds__(256) void qkv_gemm(
    const unsigned short* __restrict__ A,
    const unsigned short* __restrict__ W0, const unsigned short* __restrict__ W1,
    const unsigned short* __restrict__ W2,
    unsigned short* __restrict__ o0, unsigned short* __restrict__ o1,
    unsigned short* __restrict__ o2) {
    __shared__ unsigned short As[128][40];
    __shared__ unsigned short Bs[64][40];
    const int z = blockIdx.z;
    const unsigned short* Bt = (z == 0) ? W0 : (z == 1) ? W1 : W2;
    const int tid = threadIdx.x;
    const int wid = tid >> 6, lane = tid & 63;
    const int ln = lane & 15, g = lane >> 4;
    const int wm = wid >> 1, wn = wid & 1;
    const int bm = blockIdx.y * 128, bn = blockIdx.x * 64;

    f32x4 acc[4][2];
    #pragma unroll
    for (int i = 0; i < 4; ++i)
        #pragma unroll
        for (int j = 0; j < 2; ++j) acc[i][j] = (f32x4)0.f;

    for (int k0 = 0; k0 < C_; k0 += 32) {
        #pragma unroll
        for (int p = 0; p < 2; ++p) {
            int idx = tid + p * 256;
            int row = idx >> 2, ch = idx & 3;
            *(int4*)&As[row][ch * 8] =
                *(const int4*)&A[(size_t)(bm + row) * C_ + k0 + ch * 8];
        }
        {
            int n = tid >> 2, ch = tid & 3;
            *(int4*)&Bs[n][ch * 8] =
                *(const int4*)&Bt[(size_t)(bn + n) * C_ + k0 + ch * 8];
        }
        __syncthreads();
        short8 a[4], b[2];
        #pragma unroll
        for (int mt = 0; mt < 4; ++mt)
            a[mt] = *(const short8*)&As[wm * 64 + mt * 16 + ln][g * 8];
        #pragma unroll
        for (int nt = 0; nt < 2; ++nt)
            b[nt] = *(const short8*)&Bs[wn * 32 + nt * 16 + ln][g * 8];
        #pragma unroll
        for (int mt = 0; mt < 4; ++mt)
            #pragma unroll
            for (int nt = 0; nt < 2; ++nt)
                acc[mt][nt] = __builtin_amdgcn_mfma_f32_16x16x32_bf16(
                    a[mt], b[nt], acc[mt][nt], 0, 0, 0);
        __syncthreads();
    }

    unsigned short* outp = (z == 0) ? o0 : (z == 1) ? o1 : o2;
    #pragma unroll
    for (int mt = 0; mt < 4; ++mt) {
        #pragma unroll
        for (int nt = 0; nt < 2; ++nt) {
            f32x4 c = acc[mt][nt];
            int rowb = bm + wm * 64 + mt * 16 + g * 4;
            int col  = bn + wn * 32 + nt * 16 + ln;
            int hh = col >> 6, dd = col & 63;
            if (z < 2) {
                #pragma unroll
                for (int i = 0; i < 4; ++i) {
                    int row = rowb + i;
                    int bb = row >> 10, n = row & 1023;
                    outp[((size_t)(bb * NH_ + hh) * N_ + n) * HD_ + dd] = f2b(c[i]);
                }
            } else {
                int bb = rowb >> 10, n0 = rowb & 1023;
                ushort4 pk;
                pk.x = f2b(c[0]); pk.y = f2b(c[1]); pk.z = f2b(c[2]); pk.w = f2b(c[3]);
                *(ushort4*)&outp[((size_t)(bb * NH_ + hh) * HD_ + dd) * N_ + n0] = pk;
            }
        }
    }
}

// ---------------- proj GEMM: out = hb @ Wproj^T + bias (f32) --------------
__global__ __launch_bounds__(256) void proj_gemm(
    const unsigned short* __restrict__ A, const unsigned short* __restrict__ Bt,
    const float* __restrict__ bias, float* __restrict__ outp) {
    __shared__ unsigned short As[128][40];
    __shared__ unsigned short Bs[64][40];
    const int tid = threadIdx.x;
    const int wid = tid >> 6, lane = tid & 63;
    const int ln = lane & 15, g = lane >> 4;
    const int wm = wid >> 1, wn = wid & 1;
    const int bm = blockIdx.y * 128, bn = blockIdx.x * 64;

    f32x4 acc[4][2];
    #pragma unroll
    for (int i = 0; i < 4; ++i)
        #pragma unroll
        for (int j = 0; j < 2; ++j) acc[i][j] = (f32x4)0.f;

    for (int k0 = 0; k0 < C_; k0 += 32) {
        #pragma unroll
        for (int p = 0; p < 2; ++p) {
            int idx = tid + p * 256;
            int row = idx >> 2, ch = idx & 3;
            *(int4*)&As[row][ch * 8] =
                *(const int4*)&A[(size_t)(bm + row) * C_ + k0 + ch * 8];
        }
        {
            int n = tid >> 2, ch = tid & 3;
            *(int4*)&Bs[n][ch * 8] =
                *(const int4*)&Bt[(size_t)(bn + n) * C_ + k0 + ch * 8];
        }
        __syncthreads();
        short8 a[4], b[2];
        #pragma unroll
        for (int mt = 0; mt < 4; ++mt)
            a[mt] = *(const short8*)&As[wm * 64 + mt * 16 + ln][g * 8];
        #pragma unroll
        for (int nt = 0; nt < 2; ++nt)
            b[nt] = *(const short8*)&Bs[wn * 32 + nt * 16 + ln][g * 8];
        #pragma unroll
        for (int mt = 0; mt < 4; ++mt)
            #pragma unroll
            for (int nt = 0; nt < 2; ++nt)
                acc[mt][nt] = __builtin_amdgcn_mfma_f32_16x16x32_bf16(
                    a[mt], b[nt], acc[mt][nt], 0, 0, 0);
        __syncthreads();
    }

    #pragma unroll
    for (int mt = 0; mt < 4; ++mt) {
        #pragma unroll
        for (int nt = 0; nt < 2; ++nt) {
            f32x4 c = acc[mt][nt];
            int rowb = bm + wm * 64 + mt * 16 + g * 4;
            int col  = bn + wn * 32 + nt * 16 + ln;
            float bb = bias[col];
            #pragma unroll
            for (int i = 0; i < 4; ++i)
                outp[(size_t)(rowb + i) * C_ + col] = c[i] + bb;
        }
    }
}

// ---------------- fused attention ----------------------------------------
// 1-D grid 3072, decoded so all 8 batch-blocks of one (qb,h) land on one XCD
// (id%8 == qbh%8). 512 thr = 8 waves. sc: 32x1024 bf16, XOR-swizzled.
__global__ __launch_bounds__(512) void attn_fused(
    const unsigned short* __restrict__ qh, const unsigned short* __restrict__ kh,
    const unsigned short* __restrict__ vt,
    const unsigned short* __restrict__ bias_c,
    float* __restrict__ attn_out, unsigned short* __restrict__ hb) {
    __shared__ unsigned short sc[32 * 1024];
    __shared__ float sinv[32];
    const int id = blockIdx.x;
    const int xcd = id & 7;
    const int b = (id >> 3) & 7;
    const int qbh = ((id >> 6) << 3) + xcd;     // 0..383
    const int qb0 = (qbh / NH_) * 32;
    const int h = qbh % NH_;
    const int bh = b * NH_ + h;
    const int tid = threadIdx.x;
    const int wid = tid >> 6, lane = tid & 63;
    const int ln = lane & 15, g = lane >> 4;

    #define SCP(row, m) ((unsigned short*)((char*)sc + (row) * 2048 + \
                         (((m) * 2) ^ (((row) & 7) << 4))))

    // ---- phase 1: swapped QK^T + scale -> LDS (bf16), no bias ------------
    {
        short8 qf[2][2];
        #pragma unroll
        for (int Mt = 0; Mt < 2; ++Mt)
            #pragma unroll
            for (int kc = 0; kc < 2; ++kc)
                qf[Mt][kc] = *(const short8*)&qh[
                    ((size_t)bh * N_ + qb0 + Mt * 16 + ln) * HD_ + kc * 32 + g * 8];
        const int mb = wid * 128;
        const unsigned short* kbase = kh + (size_t)bh * N_ * HD_;
        short8 k0 = *(const short8*)&kbase[(size_t)(mb + ln) * HD_ + g * 8];
        short8 k1 = *(const short8*)&kbase[(size_t)(mb + ln) * HD_ + 32 + g * 8];
        for (int mt = 0; mt < 8; ++mt) {
            const int m0 = mb + mt * 16;
            const int m1 = (mt < 7) ? m0 + 16 : m0;     // clamped prefetch
            short8 n0 = *(const short8*)&kbase[(size_t)(m1 + ln) * HD_ + g * 8];
            short8 n1 = *(const short8*)&kbase[(size_t)(m1 + ln) * HD_ + 32 + g * 8];
            #pragma unroll
            for (int Mt = 0; Mt < 2; ++Mt) {
                f32x4 s = (f32x4)0.f;
                s = __builtin_amdgcn_mfma_f32_16x16x32_bf16(k0, qf[Mt][0], s, 0, 0, 0);
                s = __builtin_amdgcn_mfma_f32_16x16x32_bf16(k1, qf[Mt][1], s, 0, 0, 0);
                const int mrow = m0 + g * 4;
                ushort4 pk;
                pk.x = f2b(s[0] * 0.125f);
                pk.y = f2b(s[1] * 0.125f);
                pk.z = f2b(s[2] * 0.125f);
                pk.w = f2b(s[3] * 0.125f);
                *(ushort4*)SCP(Mt * 16 + ln, mrow) = pk;
            }
            k0 = n0; k1 = n1;
        }
    }
    __syncthreads();

    // ---- phase 2: + bias (coalesced), softmax; e -> LDS; attn -> global --
    {
        const int r = tid >> 4, t16 = tid & 15;
        const unsigned short* brow = bias_c + ((size_t)h * N_ + qb0 + r) * N_;
        ushort4 er[16];
        float mx = -1e30f;
        #pragma unroll
        for (int j = 0; j < 16; ++j) {
            er[j] = *(const ushort4*)SCP(r, t16 * 4 + j * 64);
            ushort4 bb = *(const ushort4*)&brow[t16 * 4 + j * 64];
            float s0 = b2f(er[j].x) + b2f(bb.x);
            float s1 = b2f(er[j].y) + b2f(bb.y);
            float s2 = b2f(er[j].z) + b2f(bb.z);
            float s3 = b2f(er[j].w) + b2f(bb.w);
            mx = fmaxf(fmaxf(fmaxf(mx, s0), fmaxf(s1, s2)), s3);
        }
        #pragma unroll
        for (int off = 8; off; off >>= 1) mx = fmaxf(mx, __shfl_xor(mx, off, 16));
        float sum = 0.f;
        #pragma unroll
        for (int j = 0; j < 16; ++j) {
            ushort4 bb = *(const ushort4*)&brow[t16 * 4 + j * 64];   // L1-hot
            float4 e;
            e.x = __expf(b2f(er[j].x) + b2f(bb.x) - mx);
            e.y = __expf(b2f(er[j].y) + b2f(bb.y) - mx);
            e.z = __expf(b2f(er[j].z) + b2f(bb.z) - mx);
            e.w = __expf(b2f(er[j].w) + b2f(bb.w) - mx);
            sum += e.x + e.y + e.z + e.w;
            er[j].x = f2b(e.x); er[j].y = f2b(e.y);
            er[j].z = f2b(e.z); er[j].w = f2b(e.w);
            *(ushort4*)SCP(r, t16 * 4 + j * 64) = er[j];
        }
        #pragma unroll
        for (int off = 8; off; off >>= 1) sum += __shfl_xor(sum, off, 16);
        const float inv = 1.f / sum;
        if (t16 == 0) sinv[r] = inv;
        float* arow = attn_out + ((size_t)bh * N_ + qb0 + r) * N_;
        #pragma unroll
        for (int j = 0; j < 16; ++j) {
            f32x4 o;
            o[0] = b2f(er[j].x) * inv;
            o[1] = b2f(er[j].y) * inv;
            o[2] = b2f(er[j].z) * inv;
            o[3] = b2f(er[j].w) * inv;
            __builtin_nontemporal_store(o, (f32x4*)&arow[t16 * 4 + j * 64]);
        }
    }
    __syncthreads();

    // ---- phase 3: PV with prefetch; scale by 1/sum at the end ------------
    {
        const int Mt = wid >> 2, nt = wid & 3;
        const unsigned short* vrow = vt + ((size_t)bh * HD_ + nt * 16 + ln) * N_;
        f32x4 acc = (f32x4)0.f;
        short8 pa = *(const short8*)SCP(Mt * 16 + ln, g * 8);
        short8 vb = *(const short8*)&vrow[g * 8];
        for (int kt = 0; kt < 32; ++kt) {
            const int knext = (kt < 31) ? kt + 1 : kt;
            short8 npa = *(const short8*)SCP(Mt * 16 + ln, knext * 32 + g * 8);
            short8 nvb = *(const short8*)&vrow[knext * 32 + g * 8];
            acc = __builtin_amdgcn_mfma_f32_16x16x32_bf16(pa, vb, acc, 0, 0, 0);
            pa = npa; vb = nvb;
        }
        #pragma unroll
        for (int i = 0; i < 4; ++i) {
            int q = qb0 + Mt * 16 + g * 4 + i;
            float o = acc[i] * sinv[Mt * 16 + g * 4 + i];
            hb[(size_t)((b << 10) + q) * C_ + h * HD_ + nt * 16 + ln] = f2b(o);
        }
    }
    #undef SCP
}

extern "C" void kernel_launch(void* const* d_in, const int* in_sizes, int n_in,
                              void* d_out, int out_size, void* d_ws, size_t ws_size,
                              hipStream_t stream) {
    const float* x         = (const float*)d_in[0];
    const float* Wq        = (const float*)d_in[1];
    const float* Wk        = (const float*)d_in[2];
    const float* Wv        = (const float*)d_in[3];
    const float* Wproj     = (const float*)d_in[4];
    const float* proj_b    = (const float*)d_in[5];
    const float* attn_bias = (const float*)d_in[6];
    const float* head_bias = (const float*)d_in[7];

    float* out  = (float*)d_out;                       // [B,N,C]
    float* attn = out + (size_t)B_ * N_ * C_;          // [B,NH,N,N]

    unsigned short* ws = (unsigned short*)d_ws;
    const size_t SZ_X = (size_t)M_ * C_;               // 6291456
    const size_t SZ_W = (size_t)C_ * C_;               // 589824
    unsigned short* xb  = ws;
    unsigned short* wqt = xb + SZ_X;
    unsigned short* wkt = wqt + SZ_W;
    unsigned short* wvt = wkt + SZ_W;
    unsigned short* wpt = wvt + SZ_W;
    unsigned short* qh  = wpt + SZ_W;     // [B,NH,N,64] bf16
    unsigned short* khd = qh + SZ_X;      // [B,NH,N,64] bf16
    unsigned short* vtp = khd + SZ_X;     // [B,NH,64,N] bf16
    unsigned short* bc  = vtp + SZ_X;     // [NH,N,N] bf16, 25.2 MB
    unsigned short* hb  = xb;             // alias: xb dead after QKV GEMMs

    cast_x_kernel<<<2048, 256, 0, stream>>>(x, xb);
    bias_combine_kernel<<<2048, 256, 0, stream>>>(attn_bias, head_bias, bc);
    transpose_cast_kernel<<<dim3(24, 24, 4), 256, 0, stream>>>(
        Wq, Wk, Wv, Wproj, wqt, wkt, wvt, wpt);

    qkv_gemm<<<dim3(C_ / 64, M_ / 128, 3), 256, 0, stream>>>(
        xb, wqt, wkt, wvt, qh, khd, vtp);

    attn_fused<<<dim3(B_ * (N_ / 32) * NH_), 512, 0, stream>>>(
        qh, khd, vtp, bc, attn, hb);

    proj_gemm<<<dim3(C_ / 64, M_ / 128), 256, 0, stream>>>(hb, wpt, proj_b, out);
}

// Round 6
// 306.378 us; speedup vs baseline: 7.1724x; 1.0129x over previous
//
#include <hip/hip_runtime.h>
#include <hip/hip_bf16.h>
#include <cstddef>

#define B_   8
#define N_   1024
#define C_   768
#define NH_  12
#define HD_  64
#define M_   (B_ * N_)   // 8192

typedef __attribute__((ext_vector_type(8))) short  short8;
typedef __attribute__((ext_vector_type(4))) float  f32x4;

__device__ __forceinline__ unsigned short f2b(float f) {
    union { float f; unsigned u; } v; v.f = f;
    unsigned u = v.u;
    return (unsigned short)((u + 0x7FFFu + ((u >> 16) & 1u)) >> 16);
}
__device__ __forceinline__ float b2f(unsigned short s) {
    union { unsigned u; float f; } v; v.u = ((unsigned)s) << 16;
    return v.f;
}
// packed f32x2 -> bf16x2 (v_cvt_pk_bf16_f32), RTNE
__device__ __forceinline__ ushort2 pk2(float a, float b) {
    __hip_bfloat162 t = __float22bfloat162_rn(make_float2(a, b));
    return *(ushort2*)&t;
}

// ---------------- cast x (f32 -> bf16), vectorized ----------------
__global__ __launch_bounds__(256) void cast_x_kernel(const float* __restrict__ x,
                                                     unsigned short* __restrict__ xb) {
    const int n4 = M_ * C_ / 4;
    for (int i = blockIdx.x * blockDim.x + threadIdx.x; i < n4; i += gridDim.x * blockDim.x) {
        float4 v = ((const float4*)x)[i];
        ushort2 lo = pk2(v.x, v.y), hi = pk2(v.z, v.w);
        ushort4 o; o.x = lo.x; o.y = lo.y; o.z = hi.x; o.w = hi.y;
        ((ushort4*)xb)[i] = o;
    }
}

// ---------------- combined bias: bc[h][q][m] = bf16(ab[q][m] + hb[h][q][m])
__global__ __launch_bounds__(256) void bias_combine_kernel(
    const float* __restrict__ ab, const float* __restrict__ hbias,
    unsigned short* __restrict__ bc) {
    const int total4 = NH_ * N_ * N_ / 4;
    const int qm4 = N_ * N_ / 4;
    for (int i = blockIdx.x * blockDim.x + threadIdx.x; i < total4; i += gridDim.x * blockDim.x) {
        int rem = i % qm4;
        float4 a = ((const float4*)ab)[rem];
        float4 h = ((const float4*)hbias)[i];
        ushort2 lo = pk2(a.x + h.x, a.y + h.y), hi = pk2(a.z + h.z, a.w + h.w);
        ushort4 o; o.x = lo.x; o.y = lo.y; o.z = hi.x; o.w = hi.y;
        ((ushort4*)bc)[i] = o;
    }
}

// ---------------- transpose + cast weights: Wt[e][c] = bf16(W[c][e]) ------
__global__ __launch_bounds__(256) void transpose_cast_kernel(
    const float* __restrict__ w0, const float* __restrict__ w1,
    const float* __restrict__ w2, const float* __restrict__ w3,
    unsigned short* __restrict__ t0, unsigned short* __restrict__ t1,
    unsigned short* __restrict__ t2, unsigned short* __restrict__ t3) {
    const int z = blockIdx.z;
    const float* src = (z == 0) ? w0 : (z == 1) ? w1 : (z == 2) ? w2 : w3;
    unsigned short* dst = (z == 0) ? t0 : (z == 1) ? t1 : (z == 2) ? t2 : t3;
    __shared__ float tile[32][33];
    const int r0 = blockIdx.y * 32, c0 = blockIdx.x * 32;
    const int tx = threadIdx.x & 31, ty = threadIdx.x >> 5;
    #pragma unroll
    for (int p = 0; p < 4; ++p)
        tile[ty + 8 * p][tx] = src[(size_t)(r0 + ty + 8 * p) * C_ + c0 + tx];
    __syncthreads();
    #pragma unroll
    for (int p = 0; p < 4; ++p)
        dst[(size_t)(c0 + ty + 8 * p) * C_ + r0 + tx] = f2b(tile[tx][ty + 8 * p]);
}

// ---------------- QKV GEMM (one dispatch, z selects weight/output) --------
__global__ __launch_bounds__(256) void qkv_gemm(
    const unsigned short* __restrict__ A,
    const unsigned short* __restrict__ W0, const unsigned short* __restrict__ W1,
    const unsigned short* __restrict__ W2,
    unsigned short* __restrict__ o0, unsigned short* __restrict__ o1,
    unsigned short* __restrict__ o2) {
    __shared__ unsigned short As[128][40];
    __shared__ unsigned short Bs[64][40];
    const int z = blockIdx.z;
    const unsigned short* Bt = (z == 0) ? W0 : (z == 1) ? W1 : W2;
    const int tid = threadIdx.x;
    const int wid = tid >> 6, lane = tid & 63;
    const int ln = lane & 15, g = lane >> 4;
    const int wm = wid >> 1, wn = wid & 1;
    const int bm = blockIdx.y * 128, bn = blockIdx.x * 64;

    f32x4 acc[4][2];
    #pragma unroll
    for (int i = 0; i < 4; ++i)
        #pragma unroll
        for (int j = 0; j < 2; ++j) acc[i][j] = (f32x4)0.f;

    for (int k0 = 0; k0 < C_; k0 += 32) {
        #pragma unroll
        for (int p = 0; p < 2; ++p) {
            int idx = tid + p * 256;
            int row = idx >> 2, ch = idx & 3;
            *(int4*)&As[row][ch * 8] =
                *(const int4*)&A[(size_t)(bm + row) * C_ + k0 + ch * 8];
        }
        {
            int n = tid >> 2, ch = tid & 3;
            *(int4*)&Bs[n][ch * 8] =
                *(const int4*)&Bt[(size_t)(bn + n) * C_ + k0 + ch * 8];
        }
        __syncthreads();
        short8 a[4], b[2];
        #pragma unroll
        for (int mt = 0; mt < 4; ++mt)
            a[mt] = *(const short8*)&As[wm * 64 + mt * 16 + ln][g * 8];
        #pragma unroll
        for (int nt = 0; nt < 2; ++nt)
            b[nt] = *(const short8*)&Bs[wn * 32 + nt * 16 + ln][g * 8];
        #pragma unroll
        for (int mt = 0; mt < 4; ++mt)
            #pragma unroll
            for (int nt = 0; nt < 2; ++nt)
                acc[mt][nt] = __builtin_amdgcn_mfma_f32_16x16x32_bf16(
                    a[mt], b[nt], acc[mt][nt], 0, 0, 0);
        __syncthreads();
    }

    unsigned short* outp = (z == 0) ? o0 : (z == 1) ? o1 : o2;
    #pragma unroll
    for (int mt = 0; mt < 4; ++mt) {
        #pragma unroll
        for (int nt = 0; nt < 2; ++nt) {
            f32x4 c = acc[mt][nt];
            int rowb = bm + wm * 64 + mt * 16 + g * 4;
            int col  = bn + wn * 32 + nt * 16 + ln;
            int hh = col >> 6, dd = col & 63;
            if (z < 2) {
                #pragma unroll
                for (int i = 0; i < 4; ++i) {
                    int row = rowb + i;
                    int bb = row >> 10, n = row & 1023;
                    outp[((size_t)(bb * NH_ + hh) * N_ + n) * HD_ + dd] = f2b(c[i]);
                }
            } else {
                int bb = rowb >> 10, n0 = rowb & 1023;
                ushort2 lo = pk2(c[0], c[1]), hi = pk2(c[2], c[3]);
                ushort4 pk; pk.x = lo.x; pk.y = lo.y; pk.z = hi.x; pk.w = hi.y;
                *(ushort4*)&outp[((size_t)(bb * NH_ + hh) * HD_ + dd) * N_ + n0] = pk;
            }
        }
    }
}

// ---------------- proj GEMM: out = hb @ Wproj^T + bias (f32) --------------
__global__ __launch_bounds__(256) void proj_gemm(
    const unsigned short* __restrict__ A, const unsigned short* __restrict__ Bt,
    const float* __restrict__ bias, float* __restrict__ outp) {
    __shared__ unsigned short As[128][40];
    __shared__ unsigned short Bs[64][40];
    const int tid = threadIdx.x;
    const int wid = tid >> 6, lane = tid & 63;
    const int ln = lane & 15, g = lane >> 4;
    const int wm = wid >> 1, wn = wid & 1;
    const int bm = blockIdx.y * 128, bn = blockIdx.x * 64;

    f32x4 acc[4][2];
    #pragma unroll
    for (int i = 0; i < 4; ++i)
        #pragma unroll
        for (int j = 0; j < 2; ++j) acc[i][j] = (f32x4)0.f;

    for (int k0 = 0; k0 < C_; k0 += 32) {
        #pragma unroll
        for (int p = 0; p < 2; ++p) {
            int idx = tid + p * 256;
            int row = idx >> 2, ch = idx & 3;
            *(int4*)&As[row][ch * 8] =
                *(const int4*)&A[(size_t)(bm + row) * C_ + k0 + ch * 8];
        }
        {
            int n = tid >> 2, ch = tid & 3;
            *(int4*)&Bs[n][ch * 8] =
                *(const int4*)&Bt[(size_t)(bn + n) * C_ + k0 + ch * 8];
        }
        __syncthreads();
        short8 a[4], b[2];
        #pragma unroll
        for (int mt = 0; mt < 4; ++mt)
            a[mt] = *(const short8*)&As[wm * 64 + mt * 16 + ln][g * 8];
        #pragma unroll
        for (int nt = 0; nt < 2; ++nt)
            b[nt] = *(const short8*)&Bs[wn * 32 + nt * 16 + ln][g * 8];
        #pragma unroll
        for (int mt = 0; mt < 4; ++mt)
            #pragma unroll
            for (int nt = 0; nt < 2; ++nt)
                acc[mt][nt] = __builtin_amdgcn_mfma_f32_16x16x32_bf16(
                    a[mt], b[nt], acc[mt][nt], 0, 0, 0);
        __syncthreads();
    }

    #pragma unroll
    for (int mt = 0; mt < 4; ++mt) {
        #pragma unroll
        for (int nt = 0; nt < 2; ++nt) {
            f32x4 c = acc[mt][nt];
            int rowb = bm + wm * 64 + mt * 16 + g * 4;
            int col  = bn + wn * 32 + nt * 16 + ln;
            float bb = bias[col];
            #pragma unroll
            for (int i = 0; i < 4; ++i)
                outp[(size_t)(rowb + i) * C_ + col] = c[i] + bb;
        }
    }
}

// ---------------- fused attention ----------------------------------------
// 1-D grid 3072, decoded so all 8 batch-blocks of one (qb,h) land on one XCD
// (id%8 == qbh%8). 512 thr = 8 waves. sc: 32x1024 bf16, XOR-swizzled.
__global__ __launch_bounds__(512) void attn_fused(
    const unsigned short* __restrict__ qh, const unsigned short* __restrict__ kh,
    const unsigned short* __restrict__ vt,
    const unsigned short* __restrict__ bias_c,
    float* __restrict__ attn_out, unsigned short* __restrict__ hb) {
    __shared__ unsigned short sc[32 * 1024];
    __shared__ float sinv[32];
    const int id = blockIdx.x;
    const int xcd = id & 7;
    const int b = (id >> 3) & 7;
    const int qbh = ((id >> 6) << 3) + xcd;     // 0..383
    const int qb0 = (qbh / NH_) * 32;
    const int h = qbh % NH_;
    const int bh = b * NH_ + h;
    const int tid = threadIdx.x;
    const int wid = tid >> 6, lane = tid & 63;
    const int ln = lane & 15, g = lane >> 4;

    #define SCP(row, m) ((unsigned short*)((char*)sc + (row) * 2048 + \
                         (((m) * 2) ^ (((row) & 7) << 4))))

    // ---- phase 1: swapped QK^T + scale -> LDS (bf16), no bias ------------
    {
        short8 qf[2][2];
        #pragma unroll
        for (int Mt = 0; Mt < 2; ++Mt)
            #pragma unroll
            for (int kc = 0; kc < 2; ++kc)
                qf[Mt][kc] = *(const short8*)&qh[
                    ((size_t)bh * N_ + qb0 + Mt * 16 + ln) * HD_ + kc * 32 + g * 8];
        const int mb = wid * 128;
        const unsigned short* kbase = kh + (size_t)bh * N_ * HD_;
        short8 k0 = *(const short8*)&kbase[(size_t)(mb + ln) * HD_ + g * 8];
        short8 k1 = *(const short8*)&kbase[(size_t)(mb + ln) * HD_ + 32 + g * 8];
        for (int mt = 0; mt < 8; ++mt) {
            const int m0 = mb + mt * 16;
            const int m1 = (mt < 7) ? m0 + 16 : m0;     // clamped prefetch
            short8 n0 = *(const short8*)&kbase[(size_t)(m1 + ln) * HD_ + g * 8];
            short8 n1 = *(const short8*)&kbase[(size_t)(m1 + ln) * HD_ + 32 + g * 8];
            #pragma unroll
            for (int Mt = 0; Mt < 2; ++Mt) {
                f32x4 s = (f32x4)0.f;
                s = __builtin_amdgcn_mfma_f32_16x16x32_bf16(k0, qf[Mt][0], s, 0, 0, 0);
                s = __builtin_amdgcn_mfma_f32_16x16x32_bf16(k1, qf[Mt][1], s, 0, 0, 0);
                const int mrow = m0 + g * 4;
                ushort2 lo = pk2(s[0] * 0.125f, s[1] * 0.125f);
                ushort2 hi = pk2(s[2] * 0.125f, s[3] * 0.125f);
                ushort4 pk; pk.x = lo.x; pk.y = lo.y; pk.z = hi.x; pk.w = hi.y;
                *(ushort4*)SCP(Mt * 16 + ln, mrow) = pk;
            }
            k0 = n0; k1 = n1;
        }
    }
    __syncthreads();

    // ---- phase 2: single-pass softmax: s in regs, e -> LDS, attn -> glob -
    {
        const int r = tid >> 4, t16 = tid & 15;
        const unsigned short* brow = bias_c + ((size_t)h * N_ + qb0 + r) * N_;
        f32x4 sv[16];                 // 64 VGPRs of scores
        float mx = -1e30f;
        #pragma unroll
        for (int j = 0; j < 16; ++j) {
            ushort4 er = *(const ushort4*)SCP(r, t16 * 4 + j * 64);
            ushort4 bb = *(const ushort4*)&brow[t16 * 4 + j * 64];
            sv[j][0] = b2f(er.x) + b2f(bb.x);
            sv[j][1] = b2f(er.y) + b2f(bb.y);
            sv[j][2] = b2f(er.z) + b2f(bb.z);
            sv[j][3] = b2f(er.w) + b2f(bb.w);
            mx = fmaxf(fmaxf(fmaxf(mx, sv[j][0]), fmaxf(sv[j][1], sv[j][2])), sv[j][3]);
        }
        #pragma unroll
        for (int off = 8; off; off >>= 1) mx = fmaxf(mx, __shfl_xor(mx, off, 16));
        float sum = 0.f;
        #pragma unroll
        for (int j = 0; j < 16; ++j) {
            float e0 = __expf(sv[j][0] - mx);
            float e1 = __expf(sv[j][1] - mx);
            float e2 = __expf(sv[j][2] - mx);
            float e3 = __expf(sv[j][3] - mx);
            sv[j][0] = e0; sv[j][1] = e1; sv[j][2] = e2; sv[j][3] = e3;
            sum += (e0 + e1) + (e2 + e3);
            ushort2 lo = pk2(e0, e1), hi = pk2(e2, e3);
            ushort4 pk; pk.x = lo.x; pk.y = lo.y; pk.z = hi.x; pk.w = hi.y;
            *(ushort4*)SCP(r, t16 * 4 + j * 64) = pk;
        }
        #pragma unroll
        for (int off = 8; off; off >>= 1) sum += __shfl_xor(sum, off, 16);
        const float inv = 1.f / sum;
        if (t16 == 0) sinv[r] = inv;
        float* arow = attn_out + ((size_t)bh * N_ + qb0 + r) * N_;
        #pragma unroll
        for (int j = 0; j < 16; ++j) {
            f32x4 o;
            o[0] = sv[j][0] * inv; o[1] = sv[j][1] * inv;
            o[2] = sv[j][2] * inv; o[3] = sv[j][3] * inv;
            __builtin_nontemporal_store(o, (f32x4*)&arow[t16 * 4 + j * 64]);
        }
    }
    __syncthreads();

    // ---- phase 3: PV with prefetch; scale by 1/sum at the end ------------
    {
        const int Mt = wid >> 2, nt = wid & 3;
        const unsigned short* vrow = vt + ((size_t)bh * HD_ + nt * 16 + ln) * N_;
        f32x4 acc = (f32x4)0.f;
        short8 pa = *(const short8*)SCP(Mt * 16 + ln, g * 8);
        short8 vb = *(const short8*)&vrow[g * 8];
        for (int kt = 0; kt < 32; ++kt) {
            const int knext = (kt < 31) ? kt + 1 : kt;
            short8 npa = *(const short8*)SCP(Mt * 16 + ln, knext * 32 + g * 8);
            short8 nvb = *(const short8*)&vrow[knext * 32 + g * 8];
            acc = __builtin_amdgcn_mfma_f32_16x16x32_bf16(pa, vb, acc, 0, 0, 0);
            pa = npa; vb = nvb;
        }
        #pragma unroll
        for (int i = 0; i < 4; ++i) {
            int q = qb0 + Mt * 16 + g * 4 + i;
            float o = acc[i] * sinv[Mt * 16 + g * 4 + i];
            hb[(size_t)((b << 10) + q) * C_ + h * HD_ + nt * 16 + ln] = f2b(o);
        }
    }
    #undef SCP
}

extern "C" void kernel_launch(void* const* d_in, const int* in_sizes, int n_in,
                              void* d_out, int out_size, void* d_ws, size_t ws_size,
                              hipStream_t stream) {
    const float* x         = (const float*)d_in[0];
    const float* Wq        = (const float*)d_in[1];
    const float* Wk        = (const float*)d_in[2];
    const float* Wv        = (const float*)d_in[3];
    const float* Wproj     = (const float*)d_in[4];
    const float* proj_b    = (const float*)d_in[5];
    const float* attn_bias = (const float*)d_in[6];
    const float* head_bias = (const float*)d_in[7];

    float* out  = (float*)d_out;                       // [B,N,C]
    float* attn = out + (size_t)B_ * N_ * C_;          // [B,NH,N,N]

    unsigned short* ws = (unsigned short*)d_ws;
    const size_t SZ_X = (size_t)M_ * C_;               // 6291456
    const size_t SZ_W = (size_t)C_ * C_;               // 589824
    unsigned short* xb  = ws;
    unsigned short* wqt = xb + SZ_X;
    unsigned short* wkt = wqt + SZ_W;
    unsigned short* wvt = wkt + SZ_W;
    unsigned short* wpt = wvt + SZ_W;
    unsigned short* qh  = wpt + SZ_W;     // [B,NH,N,64] bf16
    unsigned short* khd = qh + SZ_X;      // [B,NH,N,64] bf16
    unsigned short* vtp = khd + SZ_X;     // [B,NH,64,N] bf16
    unsigned short* bc  = vtp + SZ_X;     // [NH,N,N] bf16, 25.2 MB
    unsigned short* hb  = xb;             // alias: xb dead after QKV GEMMs

    cast_x_kernel<<<2048, 256, 0, stream>>>(x, xb);
    bias_combine_kernel<<<2048, 256, 0, stream>>>(attn_bias, head_bias, bc);
    transpose_cast_kernel<<<dim3(24, 24, 4), 256, 0, stream>>>(
        Wq, Wk, Wv, Wproj, wqt, wkt, wvt, wpt);

    qkv_gemm<<<dim3(C_ / 64, M_ / 128, 3), 256, 0, stream>>>(
        xb, wqt, wkt, wvt, qh, khd, vtp);

    attn_fused<<<dim3(B_ * (N_ / 32) * NH_), 512, 0, stream>>>(
        qh, khd, vtp, bc, attn, hb);

    proj_gemm<<<dim3(C_ / 64, M_ / 128), 256, 0, stream>>>(hb, wpt, proj_b, out);
}